// Round 1
// baseline (896.155 us; speedup 1.0000x reference)
//
#include <hip/hip_runtime.h>
#include <hip/hip_bf16.h>
#include <math.h>

#define HIDDEN 128
#define NNODES 50000
#define NEDGES 600000
#define EPS 1e-5f

// Workspace layout (bytes)
#define OFF_W6   ((size_t)0)                    // 128*768*4     = 393,216
#define OFF_AB   ((size_t)393216)               // 50000*768*4   = 153,600,000
#define OFF_AGG  ((size_t)(393216 + 153600000)) // 50000*128*4   = 25,600,000
#define OFF_CNT  ((size_t)(OFF_AGG + 25600000)) // 50000*4       = 200,000

// ---------------------------------------------------------------------------
// Kernel 1: repack Wmsg [3,256,128] into W6 [128,768]:
//   W6[k][t*128+h]       = Wmsg[t][k][h]        (src half -> A)
//   W6[k][384+t*128+h]   = Wmsg[t][128+k][h]    (dst half -> B)
__global__ __launch_bounds__(256) void build_w6(const float* __restrict__ Wmsg,
                                                float* __restrict__ W6) {
    int idx = blockIdx.x * 256 + threadIdx.x;
    if (idx >= 128 * 768) return;
    int k = idx / 768;
    int col = idx - k * 768;
    int half = col / 384;            // 0 = src half, 1 = dst half
    int rem = col - half * 384;
    int t = rem >> 7;                // /128
    int h = rem & 127;
    W6[idx] = Wmsg[t * 32768 + (half * 128 + k) * 128 + h];
}

// ---------------------------------------------------------------------------
// Kernel 2: AB[n][0:384] = x[n] @ Wsrc[t] (A), AB[n][384:768] = x[n] @ Wdst[t] + bmsg[t] (B)
// 16 nodes per block, 256 threads, each thread computes 3 output columns.
__global__ __launch_bounds__(256) void precompute_ab(const float* __restrict__ x,
                                                     const float* __restrict__ W6,
                                                     const float* __restrict__ bmsg,
                                                     float* __restrict__ AB) {
    __shared__ float xs[16][128];
    const int nb = blockIdx.x * 16;
    const int tid = threadIdx.x;

    // Stage 16 x-rows into LDS (coalesced)
    for (int i = tid; i < 16 * 128; i += 256) {
        xs[i >> 7][i & 127] = x[(size_t)nb * 128 + i];
    }
    __syncthreads();

    const int c = tid;  // columns c, c+256, c+512
    float acc0[16], acc1[16], acc2[16];
#pragma unroll
    for (int n = 0; n < 16; ++n) { acc0[n] = 0.f; acc1[n] = 0.f; acc2[n] = 0.f; }

    for (int k = 0; k < 128; k += 4) {
        float w0[4], w1[4], w2[4];
#pragma unroll
        for (int kk = 0; kk < 4; ++kk) {
            const float* wr = W6 + (size_t)(k + kk) * 768 + c;
            w0[kk] = wr[0];
            w1[kk] = wr[256];
            w2[kk] = wr[512];
        }
#pragma unroll
        for (int n = 0; n < 16; ++n) {
            float4 xv = *(const float4*)&xs[n][k];  // LDS broadcast, b128
            acc0[n] += xv.x * w0[0] + xv.y * w0[1] + xv.z * w0[2] + xv.w * w0[3];
            acc1[n] += xv.x * w1[0] + xv.y * w1[1] + xv.z * w1[2] + xv.w * w1[3];
            acc2[n] += xv.x * w2[0] + xv.y * w2[1] + xv.z * w2[2] + xv.w * w2[3];
        }
    }

    // Bias for the B half (cols >= 384): bmsg flat index = col - 384
    float b0 = (c >= 384) ? bmsg[c - 384] : 0.f;                 // c in [0,256): never
    float b1 = (c + 256 >= 384) ? bmsg[c + 256 - 384] : 0.f;
    float b2 = bmsg[c + 512 - 384];                              // always B half
#pragma unroll
    for (int n = 0; n < 16; ++n) {
        float* row = AB + (size_t)(nb + n) * 768;
        row[c] = acc0[n] + b0;
        row[c + 256] = acc1[n] + b1;
        row[c + 512] = acc2[n] + b2;
    }
}

// ---------------------------------------------------------------------------
// Kernel 3: per edge: msg = A[src][t] + B[dst][t]  -> atomicAdd into agg[dst]; count++
// One wave (64 lanes) per edge, float2 per lane. 4 edges per 256-thread block.
__global__ __launch_bounds__(256) void edge_scatter(const int* __restrict__ ei,
                                                    const int* __restrict__ et,
                                                    const float* __restrict__ AB,
                                                    float* __restrict__ agg,
                                                    float* __restrict__ cnt) {
    const int e = blockIdx.x * 4 + (threadIdx.x >> 6);
    const int lane = threadIdx.x & 63;
    if (e >= NEDGES) return;
    const int src = ei[e];
    const int dst = ei[NEDGES + e];
    const int t = et[e];

    const float2* a = (const float2*)(AB + (size_t)src * 768 + t * 128);
    const float2* b = (const float2*)(AB + (size_t)dst * 768 + 384 + t * 128);
    float2 av = a[lane];
    float2 bv = b[lane];
    float sx = av.x + bv.x;
    float sy = av.y + bv.y;

    float* aggrow = agg + (size_t)dst * 128 + lane * 2;
    atomicAdd(aggrow, sx);
    atomicAdd(aggrow + 1, sy);
    if (lane == 0) atomicAdd(cnt + dst, 1.0f);
}

// ---------------------------------------------------------------------------
// Kernel 4: h = [x, agg/max(cnt,1)] @ Wupd + bupd; LayerNorm; GELU(exact); residual.
// 8 nodes per block, 128 threads (thread j = output column j).
__global__ __launch_bounds__(128) void update_node(const float* __restrict__ x,
                                                   const float* __restrict__ agg,
                                                   const float* __restrict__ cnt,
                                                   const float* __restrict__ Wupd,
                                                   const float* __restrict__ bupd,
                                                   const float* __restrict__ gamma,
                                                   const float* __restrict__ beta,
                                                   float* __restrict__ out) {
    __shared__ float xs[8][128];
    __shared__ float as[8][128];
    __shared__ float red[8][2][2];

    const int nb = blockIdx.x * 8;
    const int j = threadIdx.x;
    const int lane = j & 63;
    const int wid = j >> 6;

#pragma unroll
    for (int n = 0; n < 8; ++n) {
        xs[n][j] = x[(size_t)(nb + n) * 128 + j];
    }
#pragma unroll
    for (int n = 0; n < 8; ++n) {
        float c = cnt[nb + n];
        float inv = 1.0f / fmaxf(c, 1.0f);
        as[n][j] = agg[(size_t)(nb + n) * 128 + j] * inv;
    }
    __syncthreads();

    float acc[8];
    float bj = bupd[j];
#pragma unroll
    for (int n = 0; n < 8; ++n) acc[n] = bj;

    // First half: x part
    for (int k = 0; k < 128; k += 4) {
        float w[4];
#pragma unroll
        for (int kk = 0; kk < 4; ++kk) w[kk] = Wupd[(size_t)(k + kk) * 128 + j];
#pragma unroll
        for (int n = 0; n < 8; ++n) {
            float4 xv = *(const float4*)&xs[n][k];
            acc[n] += xv.x * w[0] + xv.y * w[1] + xv.z * w[2] + xv.w * w[3];
        }
    }
    // Second half: agg part
    for (int k = 0; k < 128; k += 4) {
        float w[4];
#pragma unroll
        for (int kk = 0; kk < 4; ++kk) w[kk] = Wupd[(size_t)(128 + k + kk) * 128 + j];
#pragma unroll
        for (int n = 0; n < 8; ++n) {
            float4 av = *(const float4*)&as[n][k];
            acc[n] += av.x * w[0] + av.y * w[1] + av.z * w[2] + av.w * w[3];
        }
    }

    // LayerNorm reductions: sum and sumsq across 128 threads (2 waves)
#pragma unroll
    for (int n = 0; n < 8; ++n) {
        float s = acc[n];
        float s2 = acc[n] * acc[n];
#pragma unroll
        for (int off = 32; off >= 1; off >>= 1) {
            s += __shfl_xor(s, off, 64);
            s2 += __shfl_xor(s2, off, 64);
        }
        if (lane == 0) {
            red[n][wid][0] = s;
            red[n][wid][1] = s2;
        }
    }
    __syncthreads();

    const float g = gamma[j];
    const float be = beta[j];
#pragma unroll
    for (int n = 0; n < 8; ++n) {
        float s = red[n][0][0] + red[n][1][0];
        float s2 = red[n][0][1] + red[n][1][1];
        float mu = s * (1.0f / 128.0f);
        float var = s2 * (1.0f / 128.0f) - mu * mu;
        float hn = (acc[n] - mu) * rsqrtf(var + EPS) * g + be;
        float ge = 0.5f * hn * (1.0f + erff(hn * 0.70710678118654752f));
        out[(size_t)(nb + n) * 128 + j] = xs[n][j] + ge;
    }
}

// ---------------------------------------------------------------------------
extern "C" void kernel_launch(void* const* d_in, const int* in_sizes, int n_in,
                              void* d_out, int out_size, void* d_ws, size_t ws_size,
                              hipStream_t stream) {
    const float* x     = (const float*)d_in[0];
    const int*   ei    = (const int*)d_in[1];
    const int*   et    = (const int*)d_in[2];
    const float* Wmsg  = (const float*)d_in[3];
    const float* bmsg  = (const float*)d_in[4];
    const float* Wupd  = (const float*)d_in[5];
    const float* bupd  = (const float*)d_in[6];
    const float* gamma = (const float*)d_in[7];
    const float* beta  = (const float*)d_in[8];
    float* out = (float*)d_out;

    char* ws = (char*)d_ws;
    float* W6  = (float*)(ws + OFF_W6);
    float* AB  = (float*)(ws + OFF_AB);
    float* agg = (float*)(ws + OFF_AGG);
    float* cnt = (float*)(ws + OFF_CNT);

    // Zero agg + cnt (contiguous region)
    hipMemsetAsync(agg, 0, 25600000 + 200000, stream);

    build_w6<<<384, 256, 0, stream>>>(Wmsg, W6);
    precompute_ab<<<NNODES / 16, 256, 0, stream>>>(x, W6, bmsg, AB);
    edge_scatter<<<NEDGES / 4, 256, 0, stream>>>(ei, et, AB, agg, cnt);
    update_node<<<NNODES / 8, 128, 0, stream>>>(x, agg, cnt, Wupd, bupd, gamma, beta, out);
}

// Round 2
// 499.934 us; speedup vs baseline: 1.7925x; 1.7925x over previous
//
#include <hip/hip_runtime.h>
#include <hip/hip_bf16.h>
#include <math.h>

#define HIDDEN 128
#define NNODES 50000
#define NEDGES 600000
#define EPS 1e-5f
#define SCAN_CHUNK 1024
#define NSCAN_BLOCKS ((NNODES + SCAN_CHUNK - 1) / SCAN_CHUNK)  // 49

// Workspace layout (bytes)
#define OFF_W6    ((size_t)0)           // 128*768*4 = 393,216
#define OFF_AB    ((size_t)393216)      // 50000*768*4 = 153,600,000
#define OFF_AGG   ((size_t)153993216)   // 50000*128*4 = 25,600,000
#define OFF_HIST  ((size_t)179593216)   // 50000*4 -> pad 200,192
#define OFF_EXCL  ((size_t)179793408)   // 50000*4 -> pad 200,192
#define OFF_CURS  ((size_t)179993600)   // 50000*4 -> pad 200,192
#define OFF_BSUM  ((size_t)180193792)   // 49*4 -> pad 256
#define OFF_PACK  ((size_t)180194048)   // 600000*4 = 2,400,000

// ---------------------------------------------------------------------------
// Kernel 1: repack Wmsg [3,256,128] into W6 [128,768]
__global__ __launch_bounds__(256) void build_w6(const float* __restrict__ Wmsg,
                                                float* __restrict__ W6) {
    int idx = blockIdx.x * 256 + threadIdx.x;
    if (idx >= 128 * 768) return;
    int k = idx / 768;
    int col = idx - k * 768;
    int half = col / 384;
    int rem = col - half * 384;
    int t = rem >> 7;
    int h = rem & 127;
    W6[idx] = Wmsg[t * 32768 + (half * 128 + k) * 128 + h];
}

// ---------------------------------------------------------------------------
// Kernel 2: AB[n][0:384] = x[n]@Wsrc (A), AB[n][384:768] = x[n]@Wdst + bmsg (B)
__global__ __launch_bounds__(256) void precompute_ab(const float* __restrict__ x,
                                                     const float* __restrict__ W6,
                                                     const float* __restrict__ bmsg,
                                                     float* __restrict__ AB) {
    __shared__ float xs[16][128];
    const int nb = blockIdx.x * 16;
    const int tid = threadIdx.x;

    for (int i = tid; i < 16 * 128; i += 256) {
        xs[i >> 7][i & 127] = x[(size_t)nb * 128 + i];
    }
    __syncthreads();

    const int c = tid;
    float acc0[16], acc1[16], acc2[16];
#pragma unroll
    for (int n = 0; n < 16; ++n) { acc0[n] = 0.f; acc1[n] = 0.f; acc2[n] = 0.f; }

    for (int k = 0; k < 128; k += 4) {
        float w0[4], w1[4], w2[4];
#pragma unroll
        for (int kk = 0; kk < 4; ++kk) {
            const float* wr = W6 + (size_t)(k + kk) * 768 + c;
            w0[kk] = wr[0];
            w1[kk] = wr[256];
            w2[kk] = wr[512];
        }
#pragma unroll
        for (int n = 0; n < 16; ++n) {
            float4 xv = *(const float4*)&xs[n][k];
            acc0[n] += xv.x * w0[0] + xv.y * w0[1] + xv.z * w0[2] + xv.w * w0[3];
            acc1[n] += xv.x * w1[0] + xv.y * w1[1] + xv.z * w1[2] + xv.w * w1[3];
            acc2[n] += xv.x * w2[0] + xv.y * w2[1] + xv.z * w2[2] + xv.w * w2[3];
        }
    }

    float b1 = (c + 256 >= 384) ? bmsg[c + 256 - 384] : 0.f;
    float b2 = bmsg[c + 512 - 384];
#pragma unroll
    for (int n = 0; n < 16; ++n) {
        float* row = AB + (size_t)(nb + n) * 768;
        row[c] = acc0[n];
        row[c + 256] = acc1[n] + b1;
        row[c + 512] = acc2[n] + b2;
    }
}

// ---------------------------------------------------------------------------
// Kernel 3a: histogram of dst
__global__ __launch_bounds__(256) void hist_kernel(const int* __restrict__ ei,
                                                   int* __restrict__ hist) {
    int e = blockIdx.x * 256 + threadIdx.x;
    if (e >= NEDGES) return;
    atomicAdd(&hist[ei[NEDGES + e]], 1);
}

// Kernel 3b: per-chunk exclusive scan (chunk = 1024 elems, 256 thr x 4)
__global__ __launch_bounds__(256) void scan_phase1(const int* __restrict__ hist,
                                                   int* __restrict__ excl,
                                                   int* __restrict__ blockSums) {
    __shared__ int lds[256];
    const int blk = blockIdx.x;
    const int t = threadIdx.x;
    const int base = blk * SCAN_CHUNK + t * 4;
    int v[4];
    int s = 0;
#pragma unroll
    for (int i = 0; i < 4; ++i) {
        v[i] = (base + i < NNODES) ? hist[base + i] : 0;
        s += v[i];
    }
    lds[t] = s;
    __syncthreads();
    for (int off = 1; off < 256; off <<= 1) {
        int add = (t >= off) ? lds[t - off] : 0;
        __syncthreads();
        lds[t] += add;
        __syncthreads();
    }
    int incl = lds[t];
    int run = incl - s;  // exclusive prefix for this thread
#pragma unroll
    for (int i = 0; i < 4; ++i) {
        if (base + i < NNODES) excl[base + i] = run;
        run += v[i];
    }
    if (t == 255) blockSums[blk] = incl;
}

// Kernel 3c: scan the 49 block sums (trivial serial)
__global__ void scan_phase2(int* __restrict__ blockSums) {
    if (threadIdx.x == 0 && blockIdx.x == 0) {
        int run = 0;
        for (int i = 0; i < NSCAN_BLOCKS; ++i) {
            int v = blockSums[i];
            blockSums[i] = run;
            run += v;
        }
    }
}

// Kernel 3d: add block offsets; init cursor
__global__ __launch_bounds__(256) void scan_phase3(int* __restrict__ excl,
                                                   const int* __restrict__ blockSums,
                                                   int* __restrict__ cursor) {
    const int blk = blockIdx.x;
    const int add = blockSums[blk];
    for (int i = threadIdx.x; i < SCAN_CHUNK; i += 256) {
        int idx = blk * SCAN_CHUNK + i;
        if (idx < NNODES) {
            int o = excl[idx] + add;
            excl[idx] = o;
            cursor[idx] = o;
        }
    }
}

// Kernel 3e: bucket edges by dst; pack (src | t<<16) — src < 65536 fits
__global__ __launch_bounds__(256) void edge_bucket(const int* __restrict__ ei,
                                                   const int* __restrict__ et,
                                                   int* __restrict__ cursor,
                                                   unsigned* __restrict__ packed) {
    int e = blockIdx.x * 256 + threadIdx.x;
    if (e >= NEDGES) return;
    int src = ei[e];
    int dst = ei[NEDGES + e];
    int t = et[e];
    int pos = atomicAdd(&cursor[dst], 1);
    packed[pos] = (unsigned)src | ((unsigned)t << 16);
}

// ---------------------------------------------------------------------------
// Kernel 4: gather-side aggregation. One wave per node, 4 waves/block.
// agg[n] = sum_e A[src_e][t_e] + sum_t cnt_t * B[n][t]   (written once, no atomics)
__global__ __launch_bounds__(256) void aggregate(const unsigned* __restrict__ packed,
                                                 const int* __restrict__ excl,
                                                 const int* __restrict__ hist,
                                                 const float* __restrict__ AB,
                                                 float* __restrict__ agg) {
    const int n = blockIdx.x * 4 + (threadIdx.x >> 6);
    const int lane = threadIdx.x & 63;
    if (n >= NNODES) return;
    const int start = excl[n];
    const int deg = hist[n];

    float ax = 0.f, ay = 0.f;
    int c0 = 0, c1 = 0, c2 = 0;

    for (int base = 0; base < deg; base += 64) {
        const int m = min(64, deg - base);
        unsigned v = 0;
        if (lane < m) v = packed[start + base + lane];
        for (int j = 0; j < m; ++j) {
            unsigned val = __shfl(v, j, 64);
            int src = val & 0xFFFF;
            int t = val >> 16;
            c0 += (t == 0);
            c1 += (t == 1);
            c2 += (t == 2);
            float2 a = ((const float2*)(AB + (size_t)src * 768 + t * 128))[lane];
            ax += a.x;
            ay += a.y;
        }
    }

    // B-half contributions (wave-uniform branches)
    const float* browbase = AB + (size_t)n * 768 + 384;
    if (c0) {
        float2 b = ((const float2*)(browbase))[lane];
        ax += c0 * b.x; ay += c0 * b.y;
    }
    if (c1) {
        float2 b = ((const float2*)(browbase + 128))[lane];
        ax += c1 * b.x; ay += c1 * b.y;
    }
    if (c2) {
        float2 b = ((const float2*)(browbase + 256))[lane];
        ax += c2 * b.x; ay += c2 * b.y;
    }

    ((float2*)(agg + (size_t)n * 128))[lane] = make_float2(ax, ay);
}

// ---------------------------------------------------------------------------
// Kernel 5: h = [x, agg/max(deg,1)] @ Wupd + bupd; LayerNorm; GELU; residual.
__global__ __launch_bounds__(128) void update_node(const float* __restrict__ x,
                                                   const float* __restrict__ agg,
                                                   const int* __restrict__ hist,
                                                   const float* __restrict__ Wupd,
                                                   const float* __restrict__ bupd,
                                                   const float* __restrict__ gamma,
                                                   const float* __restrict__ beta,
                                                   float* __restrict__ out) {
    __shared__ float xs[8][128];
    __shared__ float as[8][128];
    __shared__ float red[8][2][2];

    const int nb = blockIdx.x * 8;
    const int j = threadIdx.x;
    const int lane = j & 63;
    const int wid = j >> 6;

#pragma unroll
    for (int n = 0; n < 8; ++n) {
        xs[n][j] = x[(size_t)(nb + n) * 128 + j];
    }
#pragma unroll
    for (int n = 0; n < 8; ++n) {
        float c = (float)hist[nb + n];
        float inv = 1.0f / fmaxf(c, 1.0f);
        as[n][j] = agg[(size_t)(nb + n) * 128 + j] * inv;
    }
    __syncthreads();

    float acc[8];
    float bj = bupd[j];
#pragma unroll
    for (int n = 0; n < 8; ++n) acc[n] = bj;

    for (int k = 0; k < 128; k += 4) {
        float w[4];
#pragma unroll
        for (int kk = 0; kk < 4; ++kk) w[kk] = Wupd[(size_t)(k + kk) * 128 + j];
#pragma unroll
        for (int n = 0; n < 8; ++n) {
            float4 xv = *(const float4*)&xs[n][k];
            acc[n] += xv.x * w[0] + xv.y * w[1] + xv.z * w[2] + xv.w * w[3];
        }
    }
    for (int k = 0; k < 128; k += 4) {
        float w[4];
#pragma unroll
        for (int kk = 0; kk < 4; ++kk) w[kk] = Wupd[(size_t)(128 + k + kk) * 128 + j];
#pragma unroll
        for (int n = 0; n < 8; ++n) {
            float4 av = *(const float4*)&as[n][k];
            acc[n] += av.x * w[0] + av.y * w[1] + av.z * w[2] + av.w * w[3];
        }
    }

#pragma unroll
    for (int n = 0; n < 8; ++n) {
        float s = acc[n];
        float s2 = acc[n] * acc[n];
#pragma unroll
        for (int off = 32; off >= 1; off >>= 1) {
            s += __shfl_xor(s, off, 64);
            s2 += __shfl_xor(s2, off, 64);
        }
        if (lane == 0) {
            red[n][wid][0] = s;
            red[n][wid][1] = s2;
        }
    }
    __syncthreads();

    const float g = gamma[j];
    const float be = beta[j];
#pragma unroll
    for (int n = 0; n < 8; ++n) {
        float s = red[n][0][0] + red[n][1][0];
        float s2 = red[n][0][1] + red[n][1][1];
        float mu = s * (1.0f / 128.0f);
        float var = s2 * (1.0f / 128.0f) - mu * mu;
        float hn = (acc[n] - mu) * rsqrtf(var + EPS) * g + be;
        float ge = 0.5f * hn * (1.0f + erff(hn * 0.70710678118654752f));
        out[(size_t)(nb + n) * 128 + j] = xs[n][j] + ge;
    }
}

// ---------------------------------------------------------------------------
extern "C" void kernel_launch(void* const* d_in, const int* in_sizes, int n_in,
                              void* d_out, int out_size, void* d_ws, size_t ws_size,
                              hipStream_t stream) {
    const float* x     = (const float*)d_in[0];
    const int*   ei    = (const int*)d_in[1];
    const int*   et    = (const int*)d_in[2];
    const float* Wmsg  = (const float*)d_in[3];
    const float* bmsg  = (const float*)d_in[4];
    const float* Wupd  = (const float*)d_in[5];
    const float* bupd  = (const float*)d_in[6];
    const float* gamma = (const float*)d_in[7];
    const float* beta  = (const float*)d_in[8];
    float* out = (float*)d_out;

    char* ws = (char*)d_ws;
    float*    W6     = (float*)(ws + OFF_W6);
    float*    AB     = (float*)(ws + OFF_AB);
    float*    agg    = (float*)(ws + OFF_AGG);
    int*      hist   = (int*)(ws + OFF_HIST);
    int*      excl   = (int*)(ws + OFF_EXCL);
    int*      cursor = (int*)(ws + OFF_CURS);
    int*      bsum   = (int*)(ws + OFF_BSUM);
    unsigned* packed = (unsigned*)(ws + OFF_PACK);

    hipMemsetAsync(hist, 0, NNODES * sizeof(int), stream);

    build_w6<<<384, 256, 0, stream>>>(Wmsg, W6);
    precompute_ab<<<NNODES / 16, 256, 0, stream>>>(x, W6, bmsg, AB);
    hist_kernel<<<(NEDGES + 255) / 256, 256, 0, stream>>>(ei, hist);
    scan_phase1<<<NSCAN_BLOCKS, 256, 0, stream>>>(hist, excl, bsum);
    scan_phase2<<<1, 64, 0, stream>>>(bsum);
    scan_phase3<<<NSCAN_BLOCKS, 256, 0, stream>>>(excl, bsum, cursor);
    edge_bucket<<<(NEDGES + 255) / 256, 256, 0, stream>>>(ei, et, cursor, packed);
    aggregate<<<(NNODES + 3) / 4, 256, 0, stream>>>(packed, excl, hist, AB, agg);
    update_node<<<NNODES / 8, 128, 0, stream>>>(x, agg, hist, Wupd, bupd, gamma, beta, out);
}

// Round 3
// 391.839 us; speedup vs baseline: 2.2871x; 1.2759x over previous
//
#include <hip/hip_runtime.h>
#include <hip/hip_bf16.h>
#include <math.h>

#define HIDDEN 128
#define NNODES 50000
#define NEDGES 600000
#define EPS 1e-5f
#define SCAN_CHUNK 1024
#define NSCAN_BLOCKS ((NNODES + SCAN_CHUNK - 1) / SCAN_CHUNK)  // 49
#define MPAD 50048  // 782 * 64

// Workspace layout (bytes)
#define OFF_W6T  ((size_t)0)            // 768*128*2 = 196,608
#define OFF_BV   ((size_t)196608)       // 768*4 = 3,072 -> ends 199,680
#define OFF_XB   ((size_t)199680)       // 50048*128*2 = 12,812,288 -> ends 13,011,968
#define OFF_ABB  ((size_t)13011968)     // 50000*768*2 = 76,800,000 -> ends 89,811,968
#define OFF_AGG  ((size_t)89811968)     // 50000*128*4 = 25,600,000 -> ends 115,411,968
#define OFF_HIST ((size_t)115411968)    // pad 200,192
#define OFF_EXCL ((size_t)115612160)
#define OFF_CURS ((size_t)115812352)
#define OFF_BSUM ((size_t)116012544)    // 256
#define OFF_PACK ((size_t)116012800)    // 600000*4

typedef __attribute__((ext_vector_type(8))) short bf16x8;
typedef __attribute__((ext_vector_type(4))) float f32x4;
typedef unsigned short ushort_t;

__device__ inline unsigned short f2bf(float f) {
    union { float f; unsigned u; } c; c.f = f;
    unsigned u = c.u;
    u += 0x7FFF + ((u >> 16) & 1);  // RNE
    return (unsigned short)(u >> 16);
}
__device__ inline float bf2f(unsigned short h) {
    union { unsigned u; float f; } c; c.u = ((unsigned)h) << 16;
    return c.f;
}

// ---------------------------------------------------------------------------
// Kernel 1a: W6T[col][k] bf16, col-major-by-output layout for B fragments.
//   col<384 (A half): W6T[col][k] = Wmsg[t][k][h]
//   col>=384 (B half): W6T[col][k] = Wmsg[t][128+k][h]
__global__ __launch_bounds__(256) void build_w6t(const float* __restrict__ Wmsg,
                                                 unsigned short* __restrict__ W6T) {
    int idx = blockIdx.x * 256 + threadIdx.x;
    if (idx >= 768 * 128) return;
    int col = idx >> 7;
    int k = idx & 127;
    int half = col >= 384;
    int rem = col - half * 384;
    int t = rem >> 7;
    int h = rem & 127;
    W6T[idx] = f2bf(Wmsg[t * 32768 + (half * 128 + k) * 128 + h]);
}

// Kernel 1b: bias vector Bv[col] (0 for A half, bmsg for B half)
__global__ __launch_bounds__(256) void build_bias(const float* __restrict__ bmsg,
                                                  float* __restrict__ Bv) {
    int idx = blockIdx.x * 256 + threadIdx.x;
    if (idx >= 768) return;
    Bv[idx] = (idx < 384) ? 0.f : bmsg[idx - 384];
}

// Kernel 1c: x fp32 -> Xb bf16, zero-padded to MPAD rows
__global__ __launch_bounds__(256) void x_to_bf16(const float* __restrict__ x,
                                                 unsigned short* __restrict__ Xb) {
    int i = blockIdx.x * 256 + threadIdx.x;         // group of 4 elements
    if (i >= MPAD * 128 / 4) return;
    int base = i * 4;
    ushort4 o;
    if (base < NNODES * 128) {
        float4 v = *(const float4*)(x + base);
        o.x = f2bf(v.x); o.y = f2bf(v.y); o.z = f2bf(v.z); o.w = f2bf(v.w);
    } else {
        o.x = o.y = o.z = o.w = 0;
    }
    *(ushort4*)(Xb + base) = o;
}

// ---------------------------------------------------------------------------
// Kernel 2: MFMA GEMM: ABb[50000][768] bf16 = Xb[50048][128] @ W6T^T + Bv
// One wave = 64x64 output tile (4x4 grid of 16x16x32 MFMAs, K=128 in 4 steps).
// Block = 4 waves covering 64 rows x 256 cols. Grid = (782, 3).
__global__ __launch_bounds__(256) void gemm_ab(const unsigned short* __restrict__ Xb,
                                               const unsigned short* __restrict__ W6T,
                                               const float* __restrict__ Bv,
                                               unsigned short* __restrict__ ABb) {
    const int mbase = blockIdx.x * 64;
    const int nbase = blockIdx.y * 256 + (threadIdx.x >> 6) * 64;
    const int lane = threadIdx.x & 63;
    const int r = lane & 15;
    const int quad = lane >> 4;

    f32x4 acc[4][4];
#pragma unroll
    for (int mi = 0; mi < 4; ++mi)
#pragma unroll
        for (int ni = 0; ni < 4; ++ni) acc[mi][ni] = (f32x4){0.f, 0.f, 0.f, 0.f};

#pragma unroll
    for (int ks = 0; ks < 4; ++ks) {
        const int koff = ks * 32 + quad * 8;
        bf16x8 a[4], b[4];
#pragma unroll
        for (int mi = 0; mi < 4; ++mi)
            a[mi] = *(const bf16x8*)(Xb + (size_t)(mbase + mi * 16 + r) * 128 + koff);
#pragma unroll
        for (int ni = 0; ni < 4; ++ni)
            b[ni] = *(const bf16x8*)(W6T + (size_t)(nbase + ni * 16 + r) * 128 + koff);
#pragma unroll
        for (int mi = 0; mi < 4; ++mi)
#pragma unroll
            for (int ni = 0; ni < 4; ++ni)
                acc[mi][ni] = __builtin_amdgcn_mfma_f32_16x16x32_bf16(a[mi], b[ni], acc[mi][ni], 0, 0, 0);
    }

    // C/D layout: col = lane&15, row = quad*4 + reg
#pragma unroll
    for (int ni = 0; ni < 4; ++ni) {
        const int col = nbase + ni * 16 + r;
        const float bias = Bv[col];
#pragma unroll
        for (int mi = 0; mi < 4; ++mi) {
            const int rowbase = mbase + mi * 16 + quad * 4;
            f32x4 v = acc[mi][ni];
#pragma unroll
            for (int reg = 0; reg < 4; ++reg) {
                int row = rowbase + reg;
                if (row < NNODES)
                    ABb[(size_t)row * 768 + col] = f2bf(v[reg] + bias);
            }
        }
    }
}

// ---------------------------------------------------------------------------
// Kernel 3a: histogram of dst
__global__ __launch_bounds__(256) void hist_kernel(const int* __restrict__ ei,
                                                   int* __restrict__ hist) {
    int e = blockIdx.x * 256 + threadIdx.x;
    if (e >= NEDGES) return;
    atomicAdd(&hist[ei[NEDGES + e]], 1);
}

// Kernel 3b: per-chunk exclusive scan
__global__ __launch_bounds__(256) void scan_phase1(const int* __restrict__ hist,
                                                   int* __restrict__ excl,
                                                   int* __restrict__ blockSums) {
    __shared__ int lds[256];
    const int blk = blockIdx.x;
    const int t = threadIdx.x;
    const int base = blk * SCAN_CHUNK + t * 4;
    int v[4];
    int s = 0;
#pragma unroll
    for (int i = 0; i < 4; ++i) {
        v[i] = (base + i < NNODES) ? hist[base + i] : 0;
        s += v[i];
    }
    lds[t] = s;
    __syncthreads();
    for (int off = 1; off < 256; off <<= 1) {
        int add = (t >= off) ? lds[t - off] : 0;
        __syncthreads();
        lds[t] += add;
        __syncthreads();
    }
    int incl = lds[t];
    int run = incl - s;
#pragma unroll
    for (int i = 0; i < 4; ++i) {
        if (base + i < NNODES) excl[base + i] = run;
        run += v[i];
    }
    if (t == 255) blockSums[blk] = incl;
}

__global__ void scan_phase2(int* __restrict__ blockSums) {
    if (threadIdx.x == 0 && blockIdx.x == 0) {
        int run = 0;
        for (int i = 0; i < NSCAN_BLOCKS; ++i) {
            int v = blockSums[i];
            blockSums[i] = run;
            run += v;
        }
    }
}

__global__ __launch_bounds__(256) void scan_phase3(int* __restrict__ excl,
                                                   const int* __restrict__ blockSums,
                                                   int* __restrict__ cursor) {
    const int blk = blockIdx.x;
    const int add = blockSums[blk];
    for (int i = threadIdx.x; i < SCAN_CHUNK; i += 256) {
        int idx = blk * SCAN_CHUNK + i;
        if (idx < NNODES) {
            int o = excl[idx] + add;
            excl[idx] = o;
            cursor[idx] = o;
        }
    }
}

// Kernel 3e: bucket edges by dst; pack (src | t<<16)
__global__ __launch_bounds__(256) void edge_bucket(const int* __restrict__ ei,
                                                   const int* __restrict__ et,
                                                   int* __restrict__ cursor,
                                                   unsigned* __restrict__ packed) {
    int e = blockIdx.x * 256 + threadIdx.x;
    if (e >= NEDGES) return;
    int src = ei[e];
    int dst = ei[NEDGES + e];
    int t = et[e];
    int pos = atomicAdd(&cursor[dst], 1);
    packed[pos] = (unsigned)src | ((unsigned)t << 16);
}

// ---------------------------------------------------------------------------
// Kernel 4: gather-side aggregation from bf16 AB. One wave per node.
__global__ __launch_bounds__(256) void aggregate(const unsigned* __restrict__ packed,
                                                 const int* __restrict__ excl,
                                                 const int* __restrict__ hist,
                                                 const unsigned short* __restrict__ ABb,
                                                 float* __restrict__ agg) {
    const int n = blockIdx.x * 4 + (threadIdx.x >> 6);
    const int lane = threadIdx.x & 63;
    if (n >= NNODES) return;
    const int start = excl[n];
    const int deg = hist[n];

    float ax = 0.f, ay = 0.f;
    int c0 = 0, c1 = 0, c2 = 0;

    for (int base = 0; base < deg; base += 64) {
        const int m = min(64, deg - base);
        unsigned v = 0;
        if (lane < m) v = packed[start + base + lane];
        for (int j = 0; j < m; ++j) {
            unsigned val = __shfl(v, j, 64);
            int src = val & 0xFFFF;
            int t = val >> 16;
            c0 += (t == 0);
            c1 += (t == 1);
            c2 += (t == 2);
            unsigned p = ((const unsigned*)(ABb + (size_t)src * 768 + t * 128))[lane];
            ax += bf2f((unsigned short)(p & 0xFFFF));
            ay += bf2f((unsigned short)(p >> 16));
        }
    }

    const unsigned short* browbase = ABb + (size_t)n * 768 + 384;
    if (c0) {
        unsigned p = ((const unsigned*)(browbase))[lane];
        ax += c0 * bf2f((unsigned short)(p & 0xFFFF));
        ay += c0 * bf2f((unsigned short)(p >> 16));
    }
    if (c1) {
        unsigned p = ((const unsigned*)(browbase + 128))[lane];
        ax += c1 * bf2f((unsigned short)(p & 0xFFFF));
        ay += c1 * bf2f((unsigned short)(p >> 16));
    }
    if (c2) {
        unsigned p = ((const unsigned*)(browbase + 256))[lane];
        ax += c2 * bf2f((unsigned short)(p & 0xFFFF));
        ay += c2 * bf2f((unsigned short)(p >> 16));
    }

    ((float2*)(agg + (size_t)n * 128))[lane] = make_float2(ax, ay);
}

// ---------------------------------------------------------------------------
// Kernel 5: h = [x, agg/max(deg,1)] @ Wupd + bupd; LayerNorm; GELU; residual.
__global__ __launch_bounds__(128) void update_node(const float* __restrict__ x,
                                                   const float* __restrict__ agg,
                                                   const int* __restrict__ hist,
                                                   const float* __restrict__ Wupd,
                                                   const float* __restrict__ bupd,
                                                   const float* __restrict__ gamma,
                                                   const float* __restrict__ beta,
                                                   float* __restrict__ out) {
    __shared__ float xs[8][128];
    __shared__ float as[8][128];
    __shared__ float red[8][2][2];

    const int nb = blockIdx.x * 8;
    const int j = threadIdx.x;
    const int lane = j & 63;
    const int wid = j >> 6;

#pragma unroll
    for (int n = 0; n < 8; ++n) {
        xs[n][j] = x[(size_t)(nb + n) * 128 + j];
    }
#pragma unroll
    for (int n = 0; n < 8; ++n) {
        float c = (float)hist[nb + n];
        float inv = 1.0f / fmaxf(c, 1.0f);
        as[n][j] = agg[(size_t)(nb + n) * 128 + j] * inv;
    }
    __syncthreads();

    float acc[8];
    float bj = bupd[j];
#pragma unroll
    for (int n = 0; n < 8; ++n) acc[n] = bj;

    for (int k = 0; k < 128; k += 4) {
        float w[4];
#pragma unroll
        for (int kk = 0; kk < 4; ++kk) w[kk] = Wupd[(size_t)(k + kk) * 128 + j];
#pragma unroll
        for (int n = 0; n < 8; ++n) {
            float4 xv = *(const float4*)&xs[n][k];
            acc[n] += xv.x * w[0] + xv.y * w[1] + xv.z * w[2] + xv.w * w[3];
        }
    }
    for (int k = 0; k < 128; k += 4) {
        float w[4];
#pragma unroll
        for (int kk = 0; kk < 4; ++kk) w[kk] = Wupd[(size_t)(128 + k + kk) * 128 + j];
#pragma unroll
        for (int n = 0; n < 8; ++n) {
            float4 av = *(const float4*)&as[n][k];
            acc[n] += av.x * w[0] + av.y * w[1] + av.z * w[2] + av.w * w[3];
        }
    }

#pragma unroll
    for (int n = 0; n < 8; ++n) {
        float s = acc[n];
        float s2 = acc[n] * acc[n];
#pragma unroll
        for (int off = 32; off >= 1; off >>= 1) {
            s += __shfl_xor(s, off, 64);
            s2 += __shfl_xor(s2, off, 64);
        }
        if (lane == 0) {
            red[n][wid][0] = s;
            red[n][wid][1] = s2;
        }
    }
    __syncthreads();

    const float g = gamma[j];
    const float be = beta[j];
#pragma unroll
    for (int n = 0; n < 8; ++n) {
        float s = red[n][0][0] + red[n][1][0];
        float s2 = red[n][0][1] + red[n][1][1];
        float mu = s * (1.0f / 128.0f);
        float var = s2 * (1.0f / 128.0f) - mu * mu;
        float hn = (acc[n] - mu) * rsqrtf(var + EPS) * g + be;
        float ge = 0.5f * hn * (1.0f + erff(hn * 0.70710678118654752f));
        out[(size_t)(nb + n) * 128 + j] = xs[n][j] + ge;
    }
}

// ---------------------------------------------------------------------------
extern "C" void kernel_launch(void* const* d_in, const int* in_sizes, int n_in,
                              void* d_out, int out_size, void* d_ws, size_t ws_size,
                              hipStream_t stream) {
    const float* x     = (const float*)d_in[0];
    const int*   ei    = (const int*)d_in[1];
    const int*   et    = (const int*)d_in[2];
    const float* Wmsg  = (const float*)d_in[3];
    const float* bmsg  = (const float*)d_in[4];
    const float* Wupd  = (const float*)d_in[5];
    const float* bupd  = (const float*)d_in[6];
    const float* gamma = (const float*)d_in[7];
    const float* beta  = (const float*)d_in[8];
    float* out = (float*)d_out;

    char* ws = (char*)d_ws;
    unsigned short* W6T  = (unsigned short*)(ws + OFF_W6T);
    float*          Bv   = (float*)(ws + OFF_BV);
    unsigned short* Xb   = (unsigned short*)(ws + OFF_XB);
    unsigned short* ABb  = (unsigned short*)(ws + OFF_ABB);
    float*          agg  = (float*)(ws + OFF_AGG);
    int*            hist = (int*)(ws + OFF_HIST);
    int*            excl = (int*)(ws + OFF_EXCL);
    int*            curs = (int*)(ws + OFF_CURS);
    int*            bsum = (int*)(ws + OFF_BSUM);
    unsigned*       pack = (unsigned*)(ws + OFF_PACK);

    hipMemsetAsync(hist, 0, NNODES * sizeof(int), stream);

    build_w6t<<<384, 256, 0, stream>>>(Wmsg, W6T);
    build_bias<<<3, 256, 0, stream>>>(bmsg, Bv);
    x_to_bf16<<<(MPAD * 128 / 4 + 255) / 256, 256, 0, stream>>>(x, Xb);
    gemm_ab<<<dim3(MPAD / 64, 3), 256, 0, stream>>>(Xb, W6T, Bv, ABb);
    hist_kernel<<<(NEDGES + 255) / 256, 256, 0, stream>>>(ei, hist);
    scan_phase1<<<NSCAN_BLOCKS, 256, 0, stream>>>(hist, excl, bsum);
    scan_phase2<<<1, 64, 0, stream>>>(bsum);
    scan_phase3<<<NSCAN_BLOCKS, 256, 0, stream>>>(excl, bsum, curs);
    edge_bucket<<<(NEDGES + 255) / 256, 256, 0, stream>>>(ei, et, curs, pack);
    aggregate<<<(NNODES + 3) / 4, 256, 0, stream>>>(pack, excl, hist, ABb, agg);
    update_node<<<NNODES / 8, 128, 0, stream>>>(x, agg, hist, Wupd, bupd, gamma, beta, out);
}

// Round 4
// 343.713 us; speedup vs baseline: 2.6073x; 1.1400x over previous
//
#include <hip/hip_runtime.h>
#include <hip/hip_bf16.h>
#include <math.h>

#define HIDDEN 128
#define NNODES 50000
#define NEDGES 600000
#define EPS 1e-5f
#define SCAN_CHUNK 1024
#define NSCAN_BLOCKS ((NNODES + SCAN_CHUNK - 1) / SCAN_CHUNK)  // 49
#define MPAD 50048  // 782 * 64

// Workspace layout (bytes), all 16B-aligned
#define OFF_W6T  ((size_t)0)            // 768*128*2   = 196,608
#define OFF_BV   ((size_t)196608)       // 768*4       = 3,072   -> 199,680
#define OFF_WUT  ((size_t)199680)       // 128*256*2   = 65,536  -> 265,216
#define OFF_XB   ((size_t)265216)       // 50048*128*2 = 12,812,288 -> 13,077,504
#define OFF_ABB  ((size_t)13077504)     // 50000*768*2 = 76,800,000 -> 89,877,504
#define OFF_AGB  ((size_t)89877504)     // 50048*128*2 = 12,812,288 -> 102,689,792
#define OFF_HIST ((size_t)102689792)    // pad 200,192 -> 102,889,984
#define OFF_EXCL ((size_t)102889984)    // -> 103,090,176
#define OFF_CURS ((size_t)103090176)    // -> 103,290,368
#define OFF_BSUM ((size_t)103290368)    // 256 -> 103,290,624
#define OFF_PACK ((size_t)103290624)    // 600000*4 = 2,400,000

typedef __attribute__((ext_vector_type(8))) short bf16x8;
typedef __attribute__((ext_vector_type(4))) float f32x4;

__device__ inline unsigned short f2bf(float f) {
    union { float f; unsigned u; } c; c.f = f;
    unsigned u = c.u;
    u += 0x7FFF + ((u >> 16) & 1);  // RNE
    return (unsigned short)(u >> 16);
}
__device__ inline float bf2f(unsigned short h) {
    union { unsigned u; float f; } c; c.u = ((unsigned)h) << 16;
    return c.f;
}

// ---------------------------------------------------------------------------
// Kernel 1a: W6T[col][k] bf16
__global__ __launch_bounds__(256) void build_w6t(const float* __restrict__ Wmsg,
                                                 unsigned short* __restrict__ W6T) {
    int idx = blockIdx.x * 256 + threadIdx.x;
    if (idx >= 768 * 128) return;
    int col = idx >> 7;
    int k = idx & 127;
    int half = col >= 384;
    int rem = col - half * 384;
    int t = rem >> 7;
    int h = rem & 127;
    W6T[idx] = f2bf(Wmsg[t * 32768 + (half * 128 + k) * 128 + h]);
}

// Kernel 1b: bias vector Bv[col]
__global__ __launch_bounds__(256) void build_bias(const float* __restrict__ bmsg,
                                                  float* __restrict__ Bv) {
    int idx = blockIdx.x * 256 + threadIdx.x;
    if (idx >= 768) return;
    Bv[idx] = (idx < 384) ? 0.f : bmsg[idx - 384];
}

// Kernel 1c: x fp32 -> Xb bf16, zero-padded to MPAD rows
__global__ __launch_bounds__(256) void x_to_bf16(const float* __restrict__ x,
                                                 unsigned short* __restrict__ Xb) {
    int i = blockIdx.x * 256 + threadIdx.x;
    if (i >= MPAD * 128 / 4) return;
    int base = i * 4;
    ushort4 o;
    if (base < NNODES * 128) {
        float4 v = *(const float4*)(x + base);
        o.x = f2bf(v.x); o.y = f2bf(v.y); o.z = f2bf(v.z); o.w = f2bf(v.w);
    } else {
        o.x = o.y = o.z = o.w = 0;
    }
    *(ushort4*)(Xb + base) = o;
}

// Kernel 1d: WupdT[n][k] bf16 = Wupd[k][n]  (n in [0,128), k in [0,256))
__global__ __launch_bounds__(256) void build_wupdt(const float* __restrict__ Wupd,
                                                   unsigned short* __restrict__ WuT) {
    int idx = blockIdx.x * 256 + threadIdx.x;
    if (idx >= 128 * 256) return;
    int n = idx >> 8;
    int k = idx & 255;
    WuT[idx] = f2bf(Wupd[(size_t)k * 128 + n]);
}

// ---------------------------------------------------------------------------
// Kernel 2: MFMA GEMM: ABb[50000][768] bf16 = Xb @ W6T^T + Bv
__global__ __launch_bounds__(256) void gemm_ab(const unsigned short* __restrict__ Xb,
                                               const unsigned short* __restrict__ W6T,
                                               const float* __restrict__ Bv,
                                               unsigned short* __restrict__ ABb) {
    const int mbase = blockIdx.x * 64;
    const int nbase = blockIdx.y * 256 + (threadIdx.x >> 6) * 64;
    const int lane = threadIdx.x & 63;
    const int r = lane & 15;
    const int quad = lane >> 4;

    f32x4 acc[4][4];
#pragma unroll
    for (int mi = 0; mi < 4; ++mi)
#pragma unroll
        for (int ni = 0; ni < 4; ++ni) acc[mi][ni] = (f32x4){0.f, 0.f, 0.f, 0.f};

#pragma unroll
    for (int ks = 0; ks < 4; ++ks) {
        const int koff = ks * 32 + quad * 8;
        bf16x8 a[4], b[4];
#pragma unroll
        for (int mi = 0; mi < 4; ++mi)
            a[mi] = *(const bf16x8*)(Xb + (size_t)(mbase + mi * 16 + r) * 128 + koff);
#pragma unroll
        for (int ni = 0; ni < 4; ++ni)
            b[ni] = *(const bf16x8*)(W6T + (size_t)(nbase + ni * 16 + r) * 128 + koff);
#pragma unroll
        for (int mi = 0; mi < 4; ++mi)
#pragma unroll
            for (int ni = 0; ni < 4; ++ni)
                acc[mi][ni] = __builtin_amdgcn_mfma_f32_16x16x32_bf16(a[mi], b[ni], acc[mi][ni], 0, 0, 0);
    }

#pragma unroll
    for (int ni = 0; ni < 4; ++ni) {
        const int col = nbase + ni * 16 + r;
        const float bias = Bv[col];
#pragma unroll
        for (int mi = 0; mi < 4; ++mi) {
            const int rowbase = mbase + mi * 16 + quad * 4;
            f32x4 v = acc[mi][ni];
#pragma unroll
            for (int reg = 0; reg < 4; ++reg) {
                int row = rowbase + reg;
                if (row < NNODES)
                    ABb[(size_t)row * 768 + col] = f2bf(v[reg] + bias);
            }
        }
    }
}

// ---------------------------------------------------------------------------
// CSR build
__global__ __launch_bounds__(256) void hist_kernel(const int* __restrict__ ei,
                                                   int* __restrict__ hist) {
    int e = blockIdx.x * 256 + threadIdx.x;
    if (e >= NEDGES) return;
    atomicAdd(&hist[ei[NEDGES + e]], 1);
}

__global__ __launch_bounds__(256) void scan_phase1(const int* __restrict__ hist,
                                                   int* __restrict__ excl,
                                                   int* __restrict__ blockSums) {
    __shared__ int lds[256];
    const int blk = blockIdx.x;
    const int t = threadIdx.x;
    const int base = blk * SCAN_CHUNK + t * 4;
    int v[4];
    int s = 0;
#pragma unroll
    for (int i = 0; i < 4; ++i) {
        v[i] = (base + i < NNODES) ? hist[base + i] : 0;
        s += v[i];
    }
    lds[t] = s;
    __syncthreads();
    for (int off = 1; off < 256; off <<= 1) {
        int add = (t >= off) ? lds[t - off] : 0;
        __syncthreads();
        lds[t] += add;
        __syncthreads();
    }
    int incl = lds[t];
    int run = incl - s;
#pragma unroll
    for (int i = 0; i < 4; ++i) {
        if (base + i < NNODES) excl[base + i] = run;
        run += v[i];
    }
    if (t == 255) blockSums[blk] = incl;
}

__global__ void scan_phase2(int* __restrict__ blockSums) {
    if (threadIdx.x == 0 && blockIdx.x == 0) {
        int run = 0;
        for (int i = 0; i < NSCAN_BLOCKS; ++i) {
            int v = blockSums[i];
            blockSums[i] = run;
            run += v;
        }
    }
}

__global__ __launch_bounds__(256) void scan_phase3(int* __restrict__ excl,
                                                   const int* __restrict__ blockSums,
                                                   int* __restrict__ cursor) {
    const int blk = blockIdx.x;
    const int add = blockSums[blk];
    for (int i = threadIdx.x; i < SCAN_CHUNK; i += 256) {
        int idx = blk * SCAN_CHUNK + i;
        if (idx < NNODES) {
            int o = excl[idx] + add;
            excl[idx] = o;
            cursor[idx] = o;
        }
    }
}

__global__ __launch_bounds__(256) void edge_bucket(const int* __restrict__ ei,
                                                   const int* __restrict__ et,
                                                   int* __restrict__ cursor,
                                                   unsigned* __restrict__ packed) {
    int e = blockIdx.x * 256 + threadIdx.x;
    if (e >= NEDGES) return;
    int src = ei[e];
    int dst = ei[NEDGES + e];
    int t = et[e];
    int pos = atomicAdd(&cursor[dst], 1);
    packed[pos] = (unsigned)src | ((unsigned)t << 16);
}

// ---------------------------------------------------------------------------
// Kernel 4: gather aggregation -> normalized bf16 agg. One wave per node.
__global__ __launch_bounds__(256) void aggregate(const unsigned* __restrict__ packed,
                                                 const int* __restrict__ excl,
                                                 const int* __restrict__ hist,
                                                 const unsigned short* __restrict__ ABb,
                                                 unsigned short* __restrict__ Agb) {
    const int n = blockIdx.x * 4 + (threadIdx.x >> 6);
    const int lane = threadIdx.x & 63;
    if (n >= NNODES) return;
    const int start = excl[n];
    const int deg = hist[n];

    float ax = 0.f, ay = 0.f;
    int c0 = 0, c1 = 0, c2 = 0;

    for (int base = 0; base < deg; base += 64) {
        const int m = min(64, deg - base);
        unsigned v = 0;
        if (lane < m) v = packed[start + base + lane];
        for (int j = 0; j < m; ++j) {
            unsigned val = __shfl(v, j, 64);
            int src = val & 0xFFFF;
            int t = val >> 16;
            c0 += (t == 0);
            c1 += (t == 1);
            c2 += (t == 2);
            unsigned p = ((const unsigned*)(ABb + (size_t)src * 768 + t * 128))[lane];
            ax += bf2f((unsigned short)(p & 0xFFFF));
            ay += bf2f((unsigned short)(p >> 16));
        }
    }

    const unsigned short* browbase = ABb + (size_t)n * 768 + 384;
    if (c0) {
        unsigned p = ((const unsigned*)(browbase))[lane];
        ax += c0 * bf2f((unsigned short)(p & 0xFFFF));
        ay += c0 * bf2f((unsigned short)(p >> 16));
    }
    if (c1) {
        unsigned p = ((const unsigned*)(browbase + 128))[lane];
        ax += c1 * bf2f((unsigned short)(p & 0xFFFF));
        ay += c1 * bf2f((unsigned short)(p >> 16));
    }
    if (c2) {
        unsigned p = ((const unsigned*)(browbase + 256))[lane];
        ax += c2 * bf2f((unsigned short)(p & 0xFFFF));
        ay += c2 * bf2f((unsigned short)(p >> 16));
    }

    const float inv = 1.0f / fmaxf((float)deg, 1.0f);
    unsigned packed_out = (unsigned)f2bf(ax * inv) | ((unsigned)f2bf(ay * inv) << 16);
    ((unsigned*)(Agb + (size_t)n * 128))[lane] = packed_out;
}

// ---------------------------------------------------------------------------
// Kernel 5: MFMA update: h = [Xb, Agb] @ WupdT^T + bupd; LN; GELU; + x; out.
// One wave = 16 rows x 128 cols. 4 waves/block => 64 rows/block. Grid = MPAD/64.
__global__ __launch_bounds__(256) void update_mfma(const unsigned short* __restrict__ Xb,
                                                   const unsigned short* __restrict__ Agb,
                                                   const unsigned short* __restrict__ WuT,
                                                   const float* __restrict__ x,
                                                   const float* __restrict__ bupd,
                                                   const float* __restrict__ gamma,
                                                   const float* __restrict__ beta,
                                                   float* __restrict__ out) {
    const int rowbase = blockIdx.x * 64 + (threadIdx.x >> 6) * 16;
    const int lane = threadIdx.x & 63;
    const int r = lane & 15;
    const int quad = lane >> 4;

    f32x4 acc[8];
#pragma unroll
    for (int ni = 0; ni < 8; ++ni) acc[ni] = (f32x4){0.f, 0.f, 0.f, 0.f};

#pragma unroll
    for (int ks = 0; ks < 8; ++ks) {
        bf16x8 a;
        if (ks < 4) {
            a = *(const bf16x8*)(Xb + (size_t)(rowbase + r) * 128 + ks * 32 + quad * 8);
        } else {
            a = *(const bf16x8*)(Agb + (size_t)(rowbase + r) * 128 + (ks - 4) * 32 + quad * 8);
        }
        bf16x8 b[8];
#pragma unroll
        for (int ni = 0; ni < 8; ++ni)
            b[ni] = *(const bf16x8*)(WuT + (size_t)(ni * 16 + r) * 256 + ks * 32 + quad * 8);
#pragma unroll
        for (int ni = 0; ni < 8; ++ni)
            acc[ni] = __builtin_amdgcn_mfma_f32_16x16x32_bf16(a, b[ni], acc[ni], 0, 0, 0);
    }

    // vals[ni][reg]: value at row = rowbase + quad*4 + reg, col = ni*16 + r
    float vals[8][4];
    float gcol[8], bcol[8];
#pragma unroll
    for (int ni = 0; ni < 8; ++ni) {
        const int col = ni * 16 + r;
        const float bias = bupd[col];
        gcol[ni] = gamma[col];
        bcol[ni] = beta[col];
#pragma unroll
        for (int reg = 0; reg < 4; ++reg) vals[ni][reg] = acc[ni][reg] + bias;
    }

#pragma unroll
    for (int reg = 0; reg < 4; ++reg) {
        float s = 0.f, s2 = 0.f;
#pragma unroll
        for (int ni = 0; ni < 8; ++ni) {
            s += vals[ni][reg];
            s2 += vals[ni][reg] * vals[ni][reg];
        }
        // reduce across the 16 lanes of this quad group
#pragma unroll
        for (int off = 8; off >= 1; off >>= 1) {
            s += __shfl_xor(s, off, 64);
            s2 += __shfl_xor(s2, off, 64);
        }
        const int row = rowbase + quad * 4 + reg;
        if (row < NNODES) {
            const float mu = s * (1.0f / 128.0f);
            const float var = s2 * (1.0f / 128.0f) - mu * mu;
            const float inv = rsqrtf(var + EPS);
#pragma unroll
            for (int ni = 0; ni < 8; ++ni) {
                const int col = ni * 16 + r;
                float hn = (vals[ni][reg] - mu) * inv * gcol[ni] + bcol[ni];
                float ge = 0.5f * hn * (1.0f + erff(hn * 0.70710678118654752f));
                out[(size_t)row * 128 + col] = x[(size_t)row * 128 + col] + ge;
            }
        }
    }
}

// ---------------------------------------------------------------------------
extern "C" void kernel_launch(void* const* d_in, const int* in_sizes, int n_in,
                              void* d_out, int out_size, void* d_ws, size_t ws_size,
                              hipStream_t stream) {
    const float* x     = (const float*)d_in[0];
    const int*   ei    = (const int*)d_in[1];
    const int*   et    = (const int*)d_in[2];
    const float* Wmsg  = (const float*)d_in[3];
    const float* bmsg  = (const float*)d_in[4];
    const float* Wupd  = (const float*)d_in[5];
    const float* bupd  = (const float*)d_in[6];
    const float* gamma = (const float*)d_in[7];
    const float* beta  = (const float*)d_in[8];
    float* out = (float*)d_out;

    char* ws = (char*)d_ws;
    unsigned short* W6T  = (unsigned short*)(ws + OFF_W6T);
    float*          Bv   = (float*)(ws + OFF_BV);
    unsigned short* WuT  = (unsigned short*)(ws + OFF_WUT);
    unsigned short* Xb   = (unsigned short*)(ws + OFF_XB);
    unsigned short* ABb  = (unsigned short*)(ws + OFF_ABB);
    unsigned short* Agb  = (unsigned short*)(ws + OFF_AGB);
    int*            hist = (int*)(ws + OFF_HIST);
    int*            excl = (int*)(ws + OFF_EXCL);
    int*            curs = (int*)(ws + OFF_CURS);
    int*            bsum = (int*)(ws + OFF_BSUM);
    unsigned*       pack = (unsigned*)(ws + OFF_PACK);

    hipMemsetAsync(hist, 0, NNODES * sizeof(int), stream);

    build_w6t<<<384, 256, 0, stream>>>(Wmsg, W6T);
    build_bias<<<3, 256, 0, stream>>>(bmsg, Bv);
    build_wupdt<<<128, 256, 0, stream>>>(Wupd, WuT);
    x_to_bf16<<<(MPAD * 128 / 4 + 255) / 256, 256, 0, stream>>>(x, Xb);
    gemm_ab<<<dim3(MPAD / 64, 3), 256, 0, stream>>>(Xb, W6T, Bv, ABb);
    hist_kernel<<<(NEDGES + 255) / 256, 256, 0, stream>>>(ei, hist);
    scan_phase1<<<NSCAN_BLOCKS, 256, 0, stream>>>(hist, excl, bsum);
    scan_phase2<<<1, 64, 0, stream>>>(bsum);
    scan_phase3<<<NSCAN_BLOCKS, 256, 0, stream>>>(excl, bsum, curs);
    edge_bucket<<<(NEDGES + 255) / 256, 256, 0, stream>>>(ei, et, curs, pack);
    aggregate<<<(NNODES + 3) / 4, 256, 0, stream>>>(pack, excl, hist, ABb, Agb);
    update_mfma<<<MPAD / 64, 256, 0, stream>>>(Xb, Agb, WuT, x, bupd, gamma, beta, out);
}

// Round 5
// 312.180 us; speedup vs baseline: 2.8706x; 1.1010x over previous
//
#include <hip/hip_runtime.h>
#include <hip/hip_bf16.h>
#include <math.h>

#define HIDDEN 128
#define NNODES 50000
#define NEDGES 600000
#define EPS 1e-5f
#define SCAN_CHUNK 1024
#define NSCAN_BLOCKS ((NNODES + SCAN_CHUNK - 1) / SCAN_CHUNK)  // 49
#define MPAD 50048  // 782 * 64

// Workspace layout (bytes), all 16B-aligned
#define OFF_W6T  ((size_t)0)            // 768*128*2   = 196,608
#define OFF_BV   ((size_t)196608)       // 768*4       = 3,072   -> 199,680
#define OFF_WUT  ((size_t)199680)       // 128*256*2   = 65,536  -> 265,216
#define OFF_XB   ((size_t)265216)       // 50048*128*2 = 12,812,288 -> 13,077,504
#define OFF_ABB  ((size_t)13077504)     // 50000*768*2 = 76,800,000 -> 89,877,504
#define OFF_AGB  ((size_t)89877504)     // 50048*128*2 = 12,812,288 -> 102,689,792
#define OFF_HIST ((size_t)102689792)    // pad 200,192 -> 102,889,984
#define OFF_EXCL ((size_t)102889984)    // -> 103,090,176
#define OFF_CURS ((size_t)103090176)    // -> 103,290,368
#define OFF_BSUM ((size_t)103290368)    // 256 -> 103,290,624
#define OFF_PACK ((size_t)103290624)    // 600000*4 = 2,400,000

typedef __attribute__((ext_vector_type(8))) short bf16x8;
typedef __attribute__((ext_vector_type(4))) float f32x4;

__device__ inline unsigned short f2bf(float f) {
    union { float f; unsigned u; } c; c.f = f;
    unsigned u = c.u;
    u += 0x7FFF + ((u >> 16) & 1);  // RNE
    return (unsigned short)(u >> 16);
}
__device__ inline float bf2f(unsigned short h) {
    union { unsigned u; float f; } c; c.u = ((unsigned)h) << 16;
    return c.f;
}

// ---------------------------------------------------------------------------
// Kernel 1: fused weight prep.
//  blocks [0,384):    W6T[col][k] bf16   (98304 elems)
//  blocks [384,387):  Bv[col]            (768 elems)
//  blocks [387,515):  WuT[n][k] bf16     (32768 elems)
__global__ __launch_bounds__(256) void prep_weights(const float* __restrict__ Wmsg,
                                                    const float* __restrict__ bmsg,
                                                    const float* __restrict__ Wupd,
                                                    unsigned short* __restrict__ W6T,
                                                    float* __restrict__ Bv,
                                                    unsigned short* __restrict__ WuT) {
    const int b = blockIdx.x;
    const int tid = threadIdx.x;
    if (b < 384) {
        int idx = b * 256 + tid;
        int col = idx >> 7;
        int k = idx & 127;
        int half = col >= 384;
        int rem = col - half * 384;
        int t = rem >> 7;
        int h = rem & 127;
        W6T[idx] = f2bf(Wmsg[t * 32768 + (half * 128 + k) * 128 + h]);
    } else if (b < 387) {
        int idx = (b - 384) * 256 + tid;
        if (idx < 768) Bv[idx] = (idx < 384) ? 0.f : bmsg[idx - 384];
    } else {
        int idx = (b - 387) * 256 + tid;
        int n = idx >> 8;
        int k = idx & 255;
        WuT[idx] = f2bf(Wupd[(size_t)k * 128 + n]);
    }
}

// Kernel 1c: x fp32 -> Xb bf16, zero-padded to MPAD rows
__global__ __launch_bounds__(256) void x_to_bf16(const float* __restrict__ x,
                                                 unsigned short* __restrict__ Xb) {
    int i = blockIdx.x * 256 + threadIdx.x;
    if (i >= MPAD * 128 / 4) return;
    int base = i * 4;
    ushort4 o;
    if (base < NNODES * 128) {
        float4 v = *(const float4*)(x + base);
        o.x = f2bf(v.x); o.y = f2bf(v.y); o.z = f2bf(v.z); o.w = f2bf(v.w);
    } else {
        o.x = o.y = o.z = o.w = 0;
    }
    *(ushort4*)(Xb + base) = o;
}

// ---------------------------------------------------------------------------
// Kernel 2: MFMA GEMM: ABb[50000][768] bf16 = Xb @ W6T^T + Bv
// One wave = 64x64 tile; block = 4 waves = 64 rows x 256 cols.
// Epilogue stages tile in LDS, then streams out coalesced 16B/lane rows.
__global__ __launch_bounds__(256) void gemm_ab(const unsigned short* __restrict__ Xb,
                                               const unsigned short* __restrict__ W6T,
                                               const float* __restrict__ Bv,
                                               unsigned short* __restrict__ ABb) {
    __shared__ unsigned short tile[64][264];  // 264 = 256 + 8 pad (bank shift)
    const int mbase = blockIdx.x * 64;
    const int w = threadIdx.x >> 6;
    const int nbase = blockIdx.y * 256 + w * 64;
    const int lane = threadIdx.x & 63;
    const int r = lane & 15;
    const int quad = lane >> 4;

    f32x4 acc[4][4];
#pragma unroll
    for (int mi = 0; mi < 4; ++mi)
#pragma unroll
        for (int ni = 0; ni < 4; ++ni) acc[mi][ni] = (f32x4){0.f, 0.f, 0.f, 0.f};

#pragma unroll
    for (int ks = 0; ks < 4; ++ks) {
        const int koff = ks * 32 + quad * 8;
        bf16x8 a[4], b[4];
#pragma unroll
        for (int mi = 0; mi < 4; ++mi)
            a[mi] = *(const bf16x8*)(Xb + (size_t)(mbase + mi * 16 + r) * 128 + koff);
#pragma unroll
        for (int ni = 0; ni < 4; ++ni)
            b[ni] = *(const bf16x8*)(W6T + (size_t)(nbase + ni * 16 + r) * 128 + koff);
#pragma unroll
        for (int mi = 0; mi < 4; ++mi)
#pragma unroll
            for (int ni = 0; ni < 4; ++ni)
                acc[mi][ni] = __builtin_amdgcn_mfma_f32_16x16x32_bf16(a[mi], b[ni], acc[mi][ni], 0, 0, 0);
    }

    // Deposit into LDS (C/D layout: col = lane&15, row = quad*4 + reg)
#pragma unroll
    for (int ni = 0; ni < 4; ++ni) {
        const int col_l = w * 64 + ni * 16 + r;
        const float bias = Bv[blockIdx.y * 256 + col_l];
#pragma unroll
        for (int mi = 0; mi < 4; ++mi) {
            f32x4 v = acc[mi][ni];
#pragma unroll
            for (int reg = 0; reg < 4; ++reg) {
                tile[mi * 16 + quad * 4 + reg][col_l] = f2bf(v[reg] + bias);
            }
        }
    }
    __syncthreads();

    // Coalesced write-out: 64 rows x 512B; 16B per thread-iteration.
    const int tid = threadIdx.x;
#pragma unroll
    for (int i = 0; i < 8; ++i) {
        int item = i * 256 + tid;         // [0, 2048)
        int row_l = item >> 5;
        int chunk = item & 31;
        int grow = mbase + row_l;
        if (grow < NNODES) {
            bf16x8 v = *(const bf16x8*)&tile[row_l][chunk * 8];
            *(bf16x8*)(ABb + (size_t)grow * 768 + blockIdx.y * 256 + chunk * 8) = v;
        }
    }
}

// ---------------------------------------------------------------------------
// CSR build
__global__ __launch_bounds__(256) void hist_kernel(const int* __restrict__ ei,
                                                   int* __restrict__ hist) {
    int e = blockIdx.x * 256 + threadIdx.x;
    if (e >= NEDGES) return;
    atomicAdd(&hist[ei[NEDGES + e]], 1);
}

__global__ __launch_bounds__(256) void scan_phase1(const int* __restrict__ hist,
                                                   int* __restrict__ excl,
                                                   int* __restrict__ blockSums) {
    __shared__ int lds[256];
    const int blk = blockIdx.x;
    const int t = threadIdx.x;
    const int base = blk * SCAN_CHUNK + t * 4;
    int v[4];
    int s = 0;
#pragma unroll
    for (int i = 0; i < 4; ++i) {
        v[i] = (base + i < NNODES) ? hist[base + i] : 0;
        s += v[i];
    }
    lds[t] = s;
    __syncthreads();
    for (int off = 1; off < 256; off <<= 1) {
        int add = (t >= off) ? lds[t - off] : 0;
        __syncthreads();
        lds[t] += add;
        __syncthreads();
    }
    int incl = lds[t];
    int run = incl - s;
#pragma unroll
    for (int i = 0; i < 4; ++i) {
        if (base + i < NNODES) excl[base + i] = run;
        run += v[i];
    }
    if (t == 255) blockSums[blk] = incl;
}

__global__ void scan_phase2(int* __restrict__ blockSums) {
    if (threadIdx.x == 0 && blockIdx.x == 0) {
        int run = 0;
        for (int i = 0; i < NSCAN_BLOCKS; ++i) {
            int v = blockSums[i];
            blockSums[i] = run;
            run += v;
        }
    }
}

__global__ __launch_bounds__(256) void scan_phase3(int* __restrict__ excl,
                                                   const int* __restrict__ blockSums,
                                                   int* __restrict__ cursor) {
    const int blk = blockIdx.x;
    const int add = blockSums[blk];
    for (int i = threadIdx.x; i < SCAN_CHUNK; i += 256) {
        int idx = blk * SCAN_CHUNK + i;
        if (idx < NNODES) {
            int o = excl[idx] + add;
            excl[idx] = o;
            cursor[idx] = o;
        }
    }
}

__global__ __launch_bounds__(256) void edge_bucket(const int* __restrict__ ei,
                                                   const int* __restrict__ et,
                                                   int* __restrict__ cursor,
                                                   unsigned* __restrict__ packed) {
    int e = blockIdx.x * 256 + threadIdx.x;
    if (e >= NEDGES) return;
    int src = ei[e];
    int dst = ei[NEDGES + e];
    int t = et[e];
    int pos = atomicAdd(&cursor[dst], 1);
    packed[pos] = (unsigned)src | ((unsigned)t << 16);
}

// ---------------------------------------------------------------------------
// Kernel 4: gather aggregation -> normalized bf16 agg. One wave per node.
__global__ __launch_bounds__(256) void aggregate(const unsigned* __restrict__ packed,
                                                 const int* __restrict__ excl,
                                                 const int* __restrict__ hist,
                                                 const unsigned short* __restrict__ ABb,
                                                 unsigned short* __restrict__ Agb) {
    const int n = blockIdx.x * 4 + (threadIdx.x >> 6);
    const int lane = threadIdx.x & 63;
    if (n >= NNODES) return;
    const int start = excl[n];
    const int deg = hist[n];

    float ax = 0.f, ay = 0.f;
    int c0 = 0, c1 = 0, c2 = 0;

    for (int base = 0; base < deg; base += 64) {
        const int m = min(64, deg - base);
        unsigned v = 0;
        if (lane < m) v = packed[start + base + lane];
        for (int j = 0; j < m; ++j) {
            unsigned val = __shfl(v, j, 64);
            int src = val & 0xFFFF;
            int t = val >> 16;
            c0 += (t == 0);
            c1 += (t == 1);
            c2 += (t == 2);
            unsigned p = ((const unsigned*)(ABb + (size_t)src * 768 + t * 128))[lane];
            ax += bf2f((unsigned short)(p & 0xFFFF));
            ay += bf2f((unsigned short)(p >> 16));
        }
    }

    const unsigned short* browbase = ABb + (size_t)n * 768 + 384;
    if (c0) {
        unsigned p = ((const unsigned*)(browbase))[lane];
        ax += c0 * bf2f((unsigned short)(p & 0xFFFF));
        ay += c0 * bf2f((unsigned short)(p >> 16));
    }
    if (c1) {
        unsigned p = ((const unsigned*)(browbase + 128))[lane];
        ax += c1 * bf2f((unsigned short)(p & 0xFFFF));
        ay += c1 * bf2f((unsigned short)(p >> 16));
    }
    if (c2) {
        unsigned p = ((const unsigned*)(browbase + 256))[lane];
        ax += c2 * bf2f((unsigned short)(p & 0xFFFF));
        ay += c2 * bf2f((unsigned short)(p >> 16));
    }

    const float inv = 1.0f / fmaxf((float)deg, 1.0f);
    unsigned packed_out = (unsigned)f2bf(ax * inv) | ((unsigned)f2bf(ay * inv) << 16);
    ((unsigned*)(Agb + (size_t)n * 128))[lane] = packed_out;
}

// ---------------------------------------------------------------------------
// Kernel 5: MFMA update: h = [Xb, Agb] @ WupdT^T + bupd; LN; GELU; + x; out.
__global__ __launch_bounds__(256) void update_mfma(const unsigned short* __restrict__ Xb,
                                                   const unsigned short* __restrict__ Agb,
                                                   const unsigned short* __restrict__ WuT,
                                                   const float* __restrict__ x,
                                                   const float* __restrict__ bupd,
                                                   const float* __restrict__ gamma,
                                                   const float* __restrict__ beta,
                                                   float* __restrict__ out) {
    const int rowbase = blockIdx.x * 64 + (threadIdx.x >> 6) * 16;
    const int lane = threadIdx.x & 63;
    const int r = lane & 15;
    const int quad = lane >> 4;

    f32x4 acc[8];
#pragma unroll
    for (int ni = 0; ni < 8; ++ni) acc[ni] = (f32x4){0.f, 0.f, 0.f, 0.f};

#pragma unroll
    for (int ks = 0; ks < 8; ++ks) {
        bf16x8 a;
        if (ks < 4) {
            a = *(const bf16x8*)(Xb + (size_t)(rowbase + r) * 128 + ks * 32 + quad * 8);
        } else {
            a = *(const bf16x8*)(Agb + (size_t)(rowbase + r) * 128 + (ks - 4) * 32 + quad * 8);
        }
        bf16x8 b[8];
#pragma unroll
        for (int ni = 0; ni < 8; ++ni)
            b[ni] = *(const bf16x8*)(WuT + (size_t)(ni * 16 + r) * 256 + ks * 32 + quad * 8);
#pragma unroll
        for (int ni = 0; ni < 8; ++ni)
            acc[ni] = __builtin_amdgcn_mfma_f32_16x16x32_bf16(a, b[ni], acc[ni], 0, 0, 0);
    }

    float vals[8][4];
    float gcol[8], bcol[8];
#pragma unroll
    for (int ni = 0; ni < 8; ++ni) {
        const int col = ni * 16 + r;
        const float bias = bupd[col];
        gcol[ni] = gamma[col];
        bcol[ni] = beta[col];
#pragma unroll
        for (int reg = 0; reg < 4; ++reg) vals[ni][reg] = acc[ni][reg] + bias;
    }

#pragma unroll
    for (int reg = 0; reg < 4; ++reg) {
        float s = 0.f, s2 = 0.f;
#pragma unroll
        for (int ni = 0; ni < 8; ++ni) {
            s += vals[ni][reg];
            s2 += vals[ni][reg] * vals[ni][reg];
        }
#pragma unroll
        for (int off = 8; off >= 1; off >>= 1) {
            s += __shfl_xor(s, off, 64);
            s2 += __shfl_xor(s2, off, 64);
        }
        const int row = rowbase + quad * 4 + reg;
        if (row < NNODES) {
            const float mu = s * (1.0f / 128.0f);
            const float var = s2 * (1.0f / 128.0f) - mu * mu;
            const float inv = rsqrtf(var + EPS);
#pragma unroll
            for (int ni = 0; ni < 8; ++ni) {
                const int col = ni * 16 + r;
                float hn = (vals[ni][reg] - mu) * inv * gcol[ni] + bcol[ni];
                float ge = 0.5f * hn * (1.0f + erff(hn * 0.70710678118654752f));
                out[(size_t)row * 128 + col] = x[(size_t)row * 128 + col] + ge;
            }
        }
    }
}

// ---------------------------------------------------------------------------
extern "C" void kernel_launch(void* const* d_in, const int* in_sizes, int n_in,
                              void* d_out, int out_size, void* d_ws, size_t ws_size,
                              hipStream_t stream) {
    const float* x     = (const float*)d_in[0];
    const int*   ei    = (const int*)d_in[1];
    const int*   et    = (const int*)d_in[2];
    const float* Wmsg  = (const float*)d_in[3];
    const float* bmsg  = (const float*)d_in[4];
    const float* Wupd  = (const float*)d_in[5];
    const float* bupd  = (const float*)d_in[6];
    const float* gamma = (const float*)d_in[7];
    const float* beta  = (const float*)d_in[8];
    float* out = (float*)d_out;

    char* ws = (char*)d_ws;
    unsigned short* W6T  = (unsigned short*)(ws + OFF_W6T);
    float*          Bv   = (float*)(ws + OFF_BV);
    unsigned short* WuT  = (unsigned short*)(ws + OFF_WUT);
    unsigned short* Xb   = (unsigned short*)(ws + OFF_XB);
    unsigned short* ABb  = (unsigned short*)(ws + OFF_ABB);
    unsigned short* Agb  = (unsigned short*)(ws + OFF_AGB);
    int*            hist = (int*)(ws + OFF_HIST);
    int*            excl = (int*)(ws + OFF_EXCL);
    int*            curs = (int*)(ws + OFF_CURS);
    int*            bsum = (int*)(ws + OFF_BSUM);
    unsigned*       pack = (unsigned*)(ws + OFF_PACK);

    hipMemsetAsync(hist, 0, NNODES * sizeof(int), stream);

    prep_weights<<<515, 256, 0, stream>>>(Wmsg, bmsg, Wupd, W6T, Bv, WuT);
    x_to_bf16<<<(MPAD * 128 / 4 + 255) / 256, 256, 0, stream>>>(x, Xb);
    gemm_ab<<<dim3(MPAD / 64, 3), 256, 0, stream>>>(Xb, W6T, Bv, ABb);
    hist_kernel<<<(NEDGES + 255) / 256, 256, 0, stream>>>(ei, hist);
    scan_phase1<<<NSCAN_BLOCKS, 256, 0, stream>>>(hist, excl, bsum);
    scan_phase2<<<1, 64, 0, stream>>>(bsum);
    scan_phase3<<<NSCAN_BLOCKS, 256, 0, stream>>>(excl, bsum, curs);
    edge_bucket<<<(NEDGES + 255) / 256, 256, 0, stream>>>(ei, et, curs, pack);
    aggregate<<<(NNODES + 3) / 4, 256, 0, stream>>>(pack, excl, hist, ABb, Agb);
    update_mfma<<<MPAD / 64, 256, 0, stream>>>(Xb, Agb, WuT, x, bupd, gamma, beta, out);
}

// Round 6
// 292.407 us; speedup vs baseline: 3.0647x; 1.0676x over previous
//
#include <hip/hip_runtime.h>
#include <hip/hip_bf16.h>
#include <math.h>

#define HIDDEN 128
#define NNODES 50000
#define NEDGES 600000
#define EPS 1e-5f
#define SCAN_CHUNK 1024
#define NSCAN_BLOCKS ((NNODES + SCAN_CHUNK - 1) / SCAN_CHUNK)  // 49
#define MPAD 50048  // 782 * 64

// Workspace layout (bytes), all 16B-aligned
#define OFF_W6T  ((size_t)0)            // 768*128*2   = 196,608
#define OFF_BV   ((size_t)196608)       // 768*4       = 3,072   -> 199,680
#define OFF_WUT  ((size_t)199680)       // 128*256*2   = 65,536  -> 265,216
#define OFF_XB   ((size_t)265216)       // 50048*128*2 = 12,812,288 -> 13,077,504
#define OFF_ABB  ((size_t)13077504)     // 50000*768*2 = 76,800,000 -> 89,877,504
#define OFF_AGB  ((size_t)89877504)     // 50048*128*2 = 12,812,288 -> 102,689,792
#define OFF_HIST ((size_t)102689792)    // pad 200,192 -> 102,889,984
#define OFF_EXCL ((size_t)102889984)    // -> 103,090,176
#define OFF_CURS ((size_t)103090176)    // -> 103,290,368
#define OFF_BSUM ((size_t)103290368)    // 256 -> 103,290,624
#define OFF_PACK ((size_t)103290624)    // 600000*4 = 2,400,000

typedef __attribute__((ext_vector_type(8))) short bf16x8;
typedef __attribute__((ext_vector_type(4))) float f32x4;

__device__ inline unsigned short f2bf(float f) {
    union { float f; unsigned u; } c; c.f = f;
    unsigned u = c.u;
    u += 0x7FFF + ((u >> 16) & 1);  // RNE
    return (unsigned short)(u >> 16);
}
__device__ inline float bf2f(unsigned short h) {
    union { unsigned u; float f; } c; c.u = ((unsigned)h) << 16;
    return c.f;
}
__device__ inline float bflo(unsigned p) { return bf2f((unsigned short)(p & 0xFFFF)); }
__device__ inline float bfhi(unsigned p) { return bf2f((unsigned short)(p >> 16)); }

// ---------------------------------------------------------------------------
// Kernel 1: fused weight prep.
__global__ __launch_bounds__(256) void prep_weights(const float* __restrict__ Wmsg,
                                                    const float* __restrict__ bmsg,
                                                    const float* __restrict__ Wupd,
                                                    unsigned short* __restrict__ W6T,
                                                    float* __restrict__ Bv,
                                                    unsigned short* __restrict__ WuT) {
    const int b = blockIdx.x;
    const int tid = threadIdx.x;
    if (b < 384) {
        int idx = b * 256 + tid;
        int col = idx >> 7;
        int k = idx & 127;
        int half = col >= 384;
        int rem = col - half * 384;
        int t = rem >> 7;
        int h = rem & 127;
        W6T[idx] = f2bf(Wmsg[t * 32768 + (half * 128 + k) * 128 + h]);
    } else if (b < 387) {
        int idx = (b - 384) * 256 + tid;
        if (idx < 768) Bv[idx] = (idx < 384) ? 0.f : bmsg[idx - 384];
    } else {
        int idx = (b - 387) * 256 + tid;
        int n = idx >> 8;
        int k = idx & 255;
        WuT[idx] = f2bf(Wupd[(size_t)k * 128 + n]);
    }
}

// Kernel 1c: x fp32 -> Xb bf16, zero-padded to MPAD rows
__global__ __launch_bounds__(256) void x_to_bf16(const float* __restrict__ x,
                                                 unsigned short* __restrict__ Xb) {
    int i = blockIdx.x * 256 + threadIdx.x;
    if (i >= MPAD * 128 / 4) return;
    int base = i * 4;
    ushort4 o;
    if (base < NNODES * 128) {
        float4 v = *(const float4*)(x + base);
        o.x = f2bf(v.x); o.y = f2bf(v.y); o.z = f2bf(v.z); o.w = f2bf(v.w);
    } else {
        o.x = o.y = o.z = o.w = 0;
    }
    *(ushort4*)(Xb + base) = o;
}

// ---------------------------------------------------------------------------
// Kernel 2: MFMA GEMM: ABb[50000][768] bf16 = Xb @ W6T^T + Bv
__global__ __launch_bounds__(256) void gemm_ab(const unsigned short* __restrict__ Xb,
                                               const unsigned short* __restrict__ W6T,
                                               const float* __restrict__ Bv,
                                               unsigned short* __restrict__ ABb) {
    __shared__ unsigned short tile[64][264];
    const int mbase = blockIdx.x * 64;
    const int w = threadIdx.x >> 6;
    const int nbase = blockIdx.y * 256 + w * 64;
    const int lane = threadIdx.x & 63;
    const int r = lane & 15;
    const int quad = lane >> 4;

    f32x4 acc[4][4];
#pragma unroll
    for (int mi = 0; mi < 4; ++mi)
#pragma unroll
        for (int ni = 0; ni < 4; ++ni) acc[mi][ni] = (f32x4){0.f, 0.f, 0.f, 0.f};

#pragma unroll
    for (int ks = 0; ks < 4; ++ks) {
        const int koff = ks * 32 + quad * 8;
        bf16x8 a[4], b[4];
#pragma unroll
        for (int mi = 0; mi < 4; ++mi)
            a[mi] = *(const bf16x8*)(Xb + (size_t)(mbase + mi * 16 + r) * 128 + koff);
#pragma unroll
        for (int ni = 0; ni < 4; ++ni)
            b[ni] = *(const bf16x8*)(W6T + (size_t)(nbase + ni * 16 + r) * 128 + koff);
#pragma unroll
        for (int mi = 0; mi < 4; ++mi)
#pragma unroll
            for (int ni = 0; ni < 4; ++ni)
                acc[mi][ni] = __builtin_amdgcn_mfma_f32_16x16x32_bf16(a[mi], b[ni], acc[mi][ni], 0, 0, 0);
    }

#pragma unroll
    for (int ni = 0; ni < 4; ++ni) {
        const int col_l = w * 64 + ni * 16 + r;
        const float bias = Bv[blockIdx.y * 256 + col_l];
#pragma unroll
        for (int mi = 0; mi < 4; ++mi) {
            f32x4 v = acc[mi][ni];
#pragma unroll
            for (int reg = 0; reg < 4; ++reg) {
                tile[mi * 16 + quad * 4 + reg][col_l] = f2bf(v[reg] + bias);
            }
        }
    }
    __syncthreads();

    const int tid = threadIdx.x;
#pragma unroll
    for (int i = 0; i < 8; ++i) {
        int item = i * 256 + tid;
        int row_l = item >> 5;
        int chunk = item & 31;
        int grow = mbase + row_l;
        if (grow < NNODES) {
            bf16x8 v = *(const bf16x8*)&tile[row_l][chunk * 8];
            *(bf16x8*)(ABb + (size_t)grow * 768 + blockIdx.y * 256 + chunk * 8) = v;
        }
    }
}

// ---------------------------------------------------------------------------
// CSR build
__global__ __launch_bounds__(256) void hist_kernel(const int* __restrict__ ei,
                                                   int* __restrict__ hist) {
    int e = blockIdx.x * 256 + threadIdx.x;
    if (e >= NEDGES) return;
    atomicAdd(&hist[ei[NEDGES + e]], 1);
}

__global__ __launch_bounds__(256) void scan_phase1(const int* __restrict__ hist,
                                                   int* __restrict__ excl,
                                                   int* __restrict__ blockSums) {
    __shared__ int lds[256];
    const int blk = blockIdx.x;
    const int t = threadIdx.x;
    const int base = blk * SCAN_CHUNK + t * 4;
    int v[4];
    int s = 0;
#pragma unroll
    for (int i = 0; i < 4; ++i) {
        v[i] = (base + i < NNODES) ? hist[base + i] : 0;
        s += v[i];
    }
    lds[t] = s;
    __syncthreads();
    for (int off = 1; off < 256; off <<= 1) {
        int add = (t >= off) ? lds[t - off] : 0;
        __syncthreads();
        lds[t] += add;
        __syncthreads();
    }
    int incl = lds[t];
    int run = incl - s;
#pragma unroll
    for (int i = 0; i < 4; ++i) {
        if (base + i < NNODES) excl[base + i] = run;
        run += v[i];
    }
    if (t == 255) blockSums[blk] = incl;
}

// scan_phase3 now also computes this block's offset (sum of earlier blockSums)
__global__ __launch_bounds__(256) void scan_phase3(int* __restrict__ excl,
                                                   const int* __restrict__ blockSums,
                                                   int* __restrict__ cursor) {
    __shared__ int s_add;
    const int blk = blockIdx.x;
    const int t = threadIdx.x;
    if (t < 64) {
        int v = (t < blk) ? blockSums[t] : 0;  // NSCAN_BLOCKS=49 < 64
#pragma unroll
        for (int off = 32; off >= 1; off >>= 1) v += __shfl_xor(v, off, 64);
        if (t == 0) s_add = v;
    }
    __syncthreads();
    const int add = s_add;
    for (int i = t; i < SCAN_CHUNK; i += 256) {
        int idx = blk * SCAN_CHUNK + i;
        if (idx < NNODES) {
            int o = excl[idx] + add;
            excl[idx] = o;
            cursor[idx] = o;
        }
    }
}

// bucket edges by dst; pack dword-offset of A-row + type:
//   packed = (src*384 + t*64) | (t << 25)    (offset < 2^25)
__global__ __launch_bounds__(256) void edge_bucket(const int* __restrict__ ei,
                                                   const int* __restrict__ et,
                                                   int* __restrict__ cursor,
                                                   unsigned* __restrict__ packed) {
    int e = blockIdx.x * 256 + threadIdx.x;
    if (e >= NEDGES) return;
    int src = ei[e];
    int dst = ei[NEDGES + e];
    int t = et[e];
    int pos = atomicAdd(&cursor[dst], 1);
    packed[pos] = (unsigned)(src * 384 + t * 64) | ((unsigned)t << 25);
}

// ---------------------------------------------------------------------------
// Kernel 4: gather aggregation -> normalized bf16 agg. One wave per node.
// Unrolled-by-4 edge walk: 4 independent loads in flight per wave.
__global__ __launch_bounds__(256) void aggregate(const unsigned* __restrict__ packed,
                                                 const int* __restrict__ excl,
                                                 const int* __restrict__ hist,
                                                 const unsigned short* __restrict__ ABb,
                                                 unsigned short* __restrict__ Agb) {
    const int n = blockIdx.x * 4 + (threadIdx.x >> 6);
    const int lane = threadIdx.x & 63;
    if (n >= NNODES) return;
    const int start = excl[n];
    const int deg = hist[n];
    const unsigned* ABu = (const unsigned*)ABb;

    float ax = 0.f, ay = 0.f;
    int c1 = 0, c2 = 0;

    for (int base = 0; base < deg; base += 64) {
        const int m = min(64, deg - base);
        unsigned v = 0;
        if (lane < m) v = packed[start + base + lane];
        int j = 0;
        for (; j + 4 <= m; j += 4) {
            unsigned v0 = __shfl(v, j, 64);
            unsigned v1 = __shfl(v, j + 1, 64);
            unsigned v2 = __shfl(v, j + 2, 64);
            unsigned v3 = __shfl(v, j + 3, 64);
            unsigned p0 = ABu[(v0 & 0x1FFFFFF) + lane];
            unsigned p1 = ABu[(v1 & 0x1FFFFFF) + lane];
            unsigned p2 = ABu[(v2 & 0x1FFFFFF) + lane];
            unsigned p3 = ABu[(v3 & 0x1FFFFFF) + lane];
            int t0 = v0 >> 25, t1 = v1 >> 25, t2 = v2 >> 25, t3 = v3 >> 25;
            c1 += (t0 == 1) + (t1 == 1) + (t2 == 1) + (t3 == 1);
            c2 += (t0 == 2) + (t1 == 2) + (t2 == 2) + (t3 == 2);
            ax += (bflo(p0) + bflo(p1)) + (bflo(p2) + bflo(p3));
            ay += (bfhi(p0) + bfhi(p1)) + (bfhi(p2) + bfhi(p3));
        }
        for (; j < m; ++j) {
            unsigned v0 = __shfl(v, j, 64);
            unsigned p0 = ABu[(v0 & 0x1FFFFFF) + lane];
            int t0 = v0 >> 25;
            c1 += (t0 == 1);
            c2 += (t0 == 2);
            ax += bflo(p0);
            ay += bfhi(p0);
        }
    }

    const int c0 = deg - c1 - c2;
    const unsigned* browbase = ABu + (size_t)n * 384 + 192;  // B half, dwords
    if (c0) {
        unsigned p = browbase[lane];
        ax += c0 * bflo(p); ay += c0 * bfhi(p);
    }
    if (c1) {
        unsigned p = browbase[64 + lane];
        ax += c1 * bflo(p); ay += c1 * bfhi(p);
    }
    if (c2) {
        unsigned p = browbase[128 + lane];
        ax += c2 * bflo(p); ay += c2 * bfhi(p);
    }

    const float inv = 1.0f / fmaxf((float)deg, 1.0f);
    unsigned packed_out = (unsigned)f2bf(ax * inv) | ((unsigned)f2bf(ay * inv) << 16);
    ((unsigned*)(Agb + (size_t)n * 128))[lane] = packed_out;
}

// ---------------------------------------------------------------------------
// Kernel 5: MFMA update: h = [Xb, Agb] @ WupdT^T + bupd; LN; GELU; + x; out.
__global__ __launch_bounds__(256) void update_mfma(const unsigned short* __restrict__ Xb,
                                                   const unsigned short* __restrict__ Agb,
                                                   const unsigned short* __restrict__ WuT,
                                                   const float* __restrict__ x,
                                                   const float* __restrict__ bupd,
                                                   const float* __restrict__ gamma,
                                                   const float* __restrict__ beta,
                                                   float* __restrict__ out) {
    const int rowbase = blockIdx.x * 64 + (threadIdx.x >> 6) * 16;
    const int lane = threadIdx.x & 63;
    const int r = lane & 15;
    const int quad = lane >> 4;

    f32x4 acc[8];
#pragma unroll
    for (int ni = 0; ni < 8; ++ni) acc[ni] = (f32x4){0.f, 0.f, 0.f, 0.f};

#pragma unroll
    for (int ks = 0; ks < 8; ++ks) {
        bf16x8 a;
        if (ks < 4) {
            a = *(const bf16x8*)(Xb + (size_t)(rowbase + r) * 128 + ks * 32 + quad * 8);
        } else {
            a = *(const bf16x8*)(Agb + (size_t)(rowbase + r) * 128 + (ks - 4) * 32 + quad * 8);
        }
        bf16x8 b[8];
#pragma unroll
        for (int ni = 0; ni < 8; ++ni)
            b[ni] = *(const bf16x8*)(WuT + (size_t)(ni * 16 + r) * 256 + ks * 32 + quad * 8);
#pragma unroll
        for (int ni = 0; ni < 8; ++ni)
            acc[ni] = __builtin_amdgcn_mfma_f32_16x16x32_bf16(a, b[ni], acc[ni], 0, 0, 0);
    }

    float vals[8][4];
    float gcol[8], bcol[8];
#pragma unroll
    for (int ni = 0; ni < 8; ++ni) {
        const int col = ni * 16 + r;
        const float bias = bupd[col];
        gcol[ni] = gamma[col];
        bcol[ni] = beta[col];
#pragma unroll
        for (int reg = 0; reg < 4; ++reg) vals[ni][reg] = acc[ni][reg] + bias;
    }

#pragma unroll
    for (int reg = 0; reg < 4; ++reg) {
        float s = 0.f, s2 = 0.f;
#pragma unroll
        for (int ni = 0; ni < 8; ++ni) {
            s += vals[ni][reg];
            s2 += vals[ni][reg] * vals[ni][reg];
        }
#pragma unroll
        for (int off = 8; off >= 1; off >>= 1) {
            s += __shfl_xor(s, off, 64);
            s2 += __shfl_xor(s2, off, 64);
        }
        const int row = rowbase + quad * 4 + reg;
        if (row < NNODES) {
            const float mu = s * (1.0f / 128.0f);
            const float var = s2 * (1.0f / 128.0f) - mu * mu;
            const float inv = rsqrtf(var + EPS);
#pragma unroll
            for (int ni = 0; ni < 8; ++ni) {
                const int col = ni * 16 + r;
                float hn = (vals[ni][reg] - mu) * inv * gcol[ni] + bcol[ni];
                float ge = 0.5f * hn * (1.0f + erff(hn * 0.70710678118654752f));
                out[(size_t)row * 128 + col] = x[(size_t)row * 128 + col] + ge;
            }
        }
    }
}

// ---------------------------------------------------------------------------
extern "C" void kernel_launch(void* const* d_in, const int* in_sizes, int n_in,
                              void* d_out, int out_size, void* d_ws, size_t ws_size,
                              hipStream_t stream) {
    const float* x     = (const float*)d_in[0];
    const int*   ei    = (const int*)d_in[1];
    const int*   et    = (const int*)d_in[2];
    const float* Wmsg  = (const float*)d_in[3];
    const float* bmsg  = (const float*)d_in[4];
    const float* Wupd  = (const float*)d_in[5];
    const float* bupd  = (const float*)d_in[6];
    const float* gamma = (const float*)d_in[7];
    const float* beta  = (const float*)d_in[8];
    float* out = (float*)d_out;

    char* ws = (char*)d_ws;
    unsigned short* W6T  = (unsigned short*)(ws + OFF_W6T);
    float*          Bv   = (float*)(ws + OFF_BV);
    unsigned short* WuT  = (unsigned short*)(ws + OFF_WUT);
    unsigned short* Xb   = (unsigned short*)(ws + OFF_XB);
    unsigned short* ABb  = (unsigned short*)(ws + OFF_ABB);
    unsigned short* Agb  = (unsigned short*)(ws + OFF_AGB);
    int*            hist = (int*)(ws + OFF_HIST);
    int*            excl = (int*)(ws + OFF_EXCL);
    int*            curs = (int*)(ws + OFF_CURS);
    int*            bsum = (int*)(ws + OFF_BSUM);
    unsigned*       pack = (unsigned*)(ws + OFF_PACK);

    hipMemsetAsync(hist, 0, NNODES * sizeof(int), stream);

    prep_weights<<<515, 256, 0, stream>>>(Wmsg, bmsg, Wupd, W6T, Bv, WuT);
    x_to_bf16<<<(MPAD * 128 / 4 + 255) / 256, 256, 0, stream>>>(x, Xb);
    gemm_ab<<<dim3(MPAD / 64, 3), 256, 0, stream>>>(Xb, W6T, Bv, ABb);
    hist_kernel<<<(NEDGES + 255) / 256, 256, 0, stream>>>(ei, hist);
    scan_phase1<<<NSCAN_BLOCKS, 256, 0, stream>>>(hist, excl, bsum);
    scan_phase3<<<NSCAN_BLOCKS, 256, 0, stream>>>(excl, bsum, curs);
    edge_bucket<<<(NEDGES + 255) / 256, 256, 0, stream>>>(ei, et, curs, pack);
    aggregate<<<(NNODES + 3) / 4, 256, 0, stream>>>(pack, excl, hist, ABb, Agb);
    update_mfma<<<MPAD / 64, 256, 0, stream>>>(Xb, Agb, WuT, x, bupd, gamma, beta, out);
}

// Round 7
// 268.624 us; speedup vs baseline: 3.3361x; 1.0885x over previous
//
#include <hip/hip_runtime.h>
#include <hip/hip_bf16.h>
#include <math.h>

#define HIDDEN 128
#define NNODES 50000
#define NEDGES 600000
#define EPS 1e-5f
#define SCAN_CHUNK 1024
#define NSCAN_BLOCKS ((NNODES + SCAN_CHUNK - 1) / SCAN_CHUNK)  // 49
#define MPAD 50048  // 782 * 64

// Workspace layout (bytes), all 16B-aligned
#define OFF_W6T  ((size_t)0)            // 768*128*2   = 196,608
#define OFF_BV   ((size_t)196608)       // 768*4       = 3,072   -> 199,680
#define OFF_WUT  ((size_t)199680)       // 128*256*2   = 65,536  -> 265,216
#define OFF_XB   ((size_t)265216)       // 50048*128*2 = 12,812,288 -> 13,077,504
#define OFF_ABB  ((size_t)13077504)     // 50000*768*2 = 76,800,000 -> 89,877,504
#define OFF_AGB  ((size_t)89877504)     // 50048*128*2 = 12,812,288 -> 102,689,792
#define OFF_HIST ((size_t)102689792)    // pad 200,192 -> 102,889,984
#define OFF_EXCL ((size_t)102889984)    // -> 103,090,176
#define OFF_CURS ((size_t)103090176)    // -> 103,290,368
#define OFF_BSUM ((size_t)103290368)    // 256 -> 103,290,624
#define OFF_PACK ((size_t)103290624)    // 600000*4 = 2,400,000

typedef __attribute__((ext_vector_type(8))) short bf16x8;
typedef __attribute__((ext_vector_type(4))) float f32x4;

__device__ inline unsigned short f2bf(float f) {
    union { float f; unsigned u; } c; c.f = f;
    unsigned u = c.u;
    u += 0x7FFF + ((u >> 16) & 1);  // RNE
    return (unsigned short)(u >> 16);
}
__device__ inline float bf2f(unsigned short h) {
    union { unsigned u; float f; } c; c.u = ((unsigned)h) << 16;
    return c.f;
}
__device__ inline float bflo(unsigned p) { return bf2f((unsigned short)(p & 0xFFFF)); }
__device__ inline float bfhi(unsigned p) { return bf2f((unsigned short)(p >> 16)); }

// ---------------------------------------------------------------------------
// Kernel 1: fused weight prep.
__global__ __launch_bounds__(256) void prep_weights(const float* __restrict__ Wmsg,
                                                    const float* __restrict__ bmsg,
                                                    const float* __restrict__ Wupd,
                                                    unsigned short* __restrict__ W6T,
                                                    float* __restrict__ Bv,
                                                    unsigned short* __restrict__ WuT) {
    const int b = blockIdx.x;
    const int tid = threadIdx.x;
    if (b < 384) {
        int idx = b * 256 + tid;
        int col = idx >> 7;
        int k = idx & 127;
        int half = col >= 384;
        int rem = col - half * 384;
        int t = rem >> 7;
        int h = rem & 127;
        W6T[idx] = f2bf(Wmsg[t * 32768 + (half * 128 + k) * 128 + h]);
    } else if (b < 387) {
        int idx = (b - 384) * 256 + tid;
        if (idx < 768) Bv[idx] = (idx < 384) ? 0.f : bmsg[idx - 384];
    } else {
        int idx = (b - 387) * 256 + tid;
        int n = idx >> 8;
        int k = idx & 255;
        WuT[idx] = f2bf(Wupd[(size_t)k * 128 + n]);
    }
}

// Kernel 1c: x fp32 -> Xb bf16, zero-padded to MPAD rows
__global__ __launch_bounds__(256) void x_to_bf16(const float* __restrict__ x,
                                                 unsigned short* __restrict__ Xb) {
    int i = blockIdx.x * 256 + threadIdx.x;
    if (i >= MPAD * 128 / 4) return;
    int base = i * 4;
    ushort4 o;
    if (base < NNODES * 128) {
        float4 v = *(const float4*)(x + base);
        o.x = f2bf(v.x); o.y = f2bf(v.y); o.z = f2bf(v.z); o.w = f2bf(v.w);
    } else {
        o.x = o.y = o.z = o.w = 0;
    }
    *(ushort4*)(Xb + base) = o;
}

// ---------------------------------------------------------------------------
// Kernel 2: MFMA GEMM: ABb[50000][768] bf16 = Xb @ W6T^T + Bv
__global__ __launch_bounds__(256) void gemm_ab(const unsigned short* __restrict__ Xb,
                                               const unsigned short* __restrict__ W6T,
                                               const float* __restrict__ Bv,
                                               unsigned short* __restrict__ ABb) {
    __shared__ unsigned short tile[64][264];
    const int mbase = blockIdx.x * 64;
    const int w = threadIdx.x >> 6;
    const int nbase = blockIdx.y * 256 + w * 64;
    const int lane = threadIdx.x & 63;
    const int r = lane & 15;
    const int quad = lane >> 4;

    f32x4 acc[4][4];
#pragma unroll
    for (int mi = 0; mi < 4; ++mi)
#pragma unroll
        for (int ni = 0; ni < 4; ++ni) acc[mi][ni] = (f32x4){0.f, 0.f, 0.f, 0.f};

#pragma unroll
    for (int ks = 0; ks < 4; ++ks) {
        const int koff = ks * 32 + quad * 8;
        bf16x8 a[4], b[4];
#pragma unroll
        for (int mi = 0; mi < 4; ++mi)
            a[mi] = *(const bf16x8*)(Xb + (size_t)(mbase + mi * 16 + r) * 128 + koff);
#pragma unroll
        for (int ni = 0; ni < 4; ++ni)
            b[ni] = *(const bf16x8*)(W6T + (size_t)(nbase + ni * 16 + r) * 128 + koff);
#pragma unroll
        for (int mi = 0; mi < 4; ++mi)
#pragma unroll
            for (int ni = 0; ni < 4; ++ni)
                acc[mi][ni] = __builtin_amdgcn_mfma_f32_16x16x32_bf16(a[mi], b[ni], acc[mi][ni], 0, 0, 0);
    }

#pragma unroll
    for (int ni = 0; ni < 4; ++ni) {
        const int col_l = w * 64 + ni * 16 + r;
        const float bias = Bv[blockIdx.y * 256 + col_l];
#pragma unroll
        for (int mi = 0; mi < 4; ++mi) {
            f32x4 v = acc[mi][ni];
#pragma unroll
            for (int reg = 0; reg < 4; ++reg) {
                tile[mi * 16 + quad * 4 + reg][col_l] = f2bf(v[reg] + bias);
            }
        }
    }
    __syncthreads();

    const int tid = threadIdx.x;
#pragma unroll
    for (int i = 0; i < 8; ++i) {
        int item = i * 256 + tid;
        int row_l = item >> 5;
        int chunk = item & 31;
        int grow = mbase + row_l;
        if (grow < NNODES) {
            bf16x8 v = *(const bf16x8*)&tile[row_l][chunk * 8];
            *(bf16x8*)(ABb + (size_t)grow * 768 + blockIdx.y * 256 + chunk * 8) = v;
        }
    }
}

// ---------------------------------------------------------------------------
// CSR build
__global__ __launch_bounds__(256) void hist_kernel(const int* __restrict__ ei,
                                                   int* __restrict__ hist) {
    int e = blockIdx.x * 256 + threadIdx.x;
    if (e >= NEDGES) return;
    atomicAdd(&hist[ei[NEDGES + e]], 1);
}

__global__ __launch_bounds__(256) void scan_phase1(const int* __restrict__ hist,
                                                   int* __restrict__ excl,
                                                   int* __restrict__ blockSums) {
    __shared__ int lds[256];
    const int blk = blockIdx.x;
    const int t = threadIdx.x;
    const int base = blk * SCAN_CHUNK + t * 4;
    int v[4];
    int s = 0;
#pragma unroll
    for (int i = 0; i < 4; ++i) {
        v[i] = (base + i < NNODES) ? hist[base + i] : 0;
        s += v[i];
    }
    lds[t] = s;
    __syncthreads();
    for (int off = 1; off < 256; off <<= 1) {
        int add = (t >= off) ? lds[t - off] : 0;
        __syncthreads();
        lds[t] += add;
        __syncthreads();
    }
    int incl = lds[t];
    int run = incl - s;
#pragma unroll
    for (int i = 0; i < 4; ++i) {
        if (base + i < NNODES) excl[base + i] = run;
        run += v[i];
    }
    if (t == 255) blockSums[blk] = incl;
}

__global__ __launch_bounds__(256) void scan_phase3(int* __restrict__ excl,
                                                   const int* __restrict__ blockSums,
                                                   int* __restrict__ cursor) {
    __shared__ int s_add;
    const int blk = blockIdx.x;
    const int t = threadIdx.x;
    if (t < 64) {
        int v = (t < blk) ? blockSums[t] : 0;
#pragma unroll
        for (int off = 32; off >= 1; off >>= 1) v += __shfl_xor(v, off, 64);
        if (t == 0) s_add = v;
    }
    __syncthreads();
    const int add = s_add;
    for (int i = t; i < SCAN_CHUNK; i += 256) {
        int idx = blk * SCAN_CHUNK + i;
        if (idx < NNODES) {
            int o = excl[idx] + add;
            excl[idx] = o;
            cursor[idx] = o;
        }
    }
}

__global__ __launch_bounds__(256) void edge_bucket(const int* __restrict__ ei,
                                                   const int* __restrict__ et,
                                                   int* __restrict__ cursor,
                                                   unsigned* __restrict__ packed) {
    int e = blockIdx.x * 256 + threadIdx.x;
    if (e >= NEDGES) return;
    int src = ei[e];
    int dst = ei[NEDGES + e];
    int t = et[e];
    int pos = atomicAdd(&cursor[dst], 1);
    packed[pos] = (unsigned)(src * 384 + t * 64) | ((unsigned)t << 25);
}

// ---------------------------------------------------------------------------
// Kernel 4: gather aggregation -> normalized bf16 agg. One wave per node.
__global__ __launch_bounds__(256) void aggregate(const unsigned* __restrict__ packed,
                                                 const int* __restrict__ excl,
                                                 const int* __restrict__ hist,
                                                 const unsigned short* __restrict__ ABb,
                                                 unsigned short* __restrict__ Agb) {
    const int n = blockIdx.x * 4 + (threadIdx.x >> 6);
    const int lane = threadIdx.x & 63;
    if (n >= NNODES) return;
    const int start = excl[n];
    const int deg = hist[n];
    const unsigned* ABu = (const unsigned*)ABb;

    float ax = 0.f, ay = 0.f;
    int c1 = 0, c2 = 0;

    for (int base = 0; base < deg; base += 64) {
        const int m = min(64, deg - base);
        unsigned v = 0;
        if (lane < m) v = packed[start + base + lane];
        int j = 0;
        for (; j + 4 <= m; j += 4) {
            unsigned v0 = __shfl(v, j, 64);
            unsigned v1 = __shfl(v, j + 1, 64);
            unsigned v2 = __shfl(v, j + 2, 64);
            unsigned v3 = __shfl(v, j + 3, 64);
            unsigned p0 = ABu[(v0 & 0x1FFFFFF) + lane];
            unsigned p1 = ABu[(v1 & 0x1FFFFFF) + lane];
            unsigned p2 = ABu[(v2 & 0x1FFFFFF) + lane];
            unsigned p3 = ABu[(v3 & 0x1FFFFFF) + lane];
            int t0 = v0 >> 25, t1 = v1 >> 25, t2 = v2 >> 25, t3 = v3 >> 25;
            c1 += (t0 == 1) + (t1 == 1) + (t2 == 1) + (t3 == 1);
            c2 += (t0 == 2) + (t1 == 2) + (t2 == 2) + (t3 == 2);
            ax += (bflo(p0) + bflo(p1)) + (bflo(p2) + bflo(p3));
            ay += (bfhi(p0) + bfhi(p1)) + (bfhi(p2) + bfhi(p3));
        }
        for (; j < m; ++j) {
            unsigned v0 = __shfl(v, j, 64);
            unsigned p0 = ABu[(v0 & 0x1FFFFFF) + lane];
            int t0 = v0 >> 25;
            c1 += (t0 == 1);
            c2 += (t0 == 2);
            ax += bflo(p0);
            ay += bfhi(p0);
        }
    }

    const int c0 = deg - c1 - c2;
    const unsigned* browbase = ABu + (size_t)n * 384 + 192;
    if (c0) {
        unsigned p = browbase[lane];
        ax += c0 * bflo(p); ay += c0 * bfhi(p);
    }
    if (c1) {
        unsigned p = browbase[64 + lane];
        ax += c1 * bflo(p); ay += c1 * bfhi(p);
    }
    if (c2) {
        unsigned p = browbase[128 + lane];
        ax += c2 * bflo(p); ay += c2 * bfhi(p);
    }

    const float inv = 1.0f / fmaxf((float)deg, 1.0f);
    unsigned packed_out = (unsigned)f2bf(ax * inv) | ((unsigned)f2bf(ay * inv) << 16);
    ((unsigned*)(Agb + (size_t)n * 128))[lane] = packed_out;
}

// ---------------------------------------------------------------------------
// Kernel 5: MFMA update with LDS-staged WuT (XOR-swizzled, 64 KB).
// h = [Xb, Agb] @ WupdT^T + bupd; LN; GELU; + x; out.
__global__ __launch_bounds__(256) void update_mfma(const unsigned short* __restrict__ Xb,
                                                   const unsigned short* __restrict__ Agb,
                                                   const unsigned short* __restrict__ WuT,
                                                   const float* __restrict__ x,
                                                   const float* __restrict__ bupd,
                                                   const float* __restrict__ gamma,
                                                   const float* __restrict__ beta,
                                                   float* __restrict__ out) {
    __shared__ unsigned short wut_lds[128 * 256];  // 64 KB, swizzled

    const int tid = threadIdx.x;
    const int rowbase = blockIdx.x * 64 + (tid >> 6) * 16;
    const int lane = tid & 63;
    const int r = lane & 15;
    const int quad = lane >> 4;

    // Hoisted independent loads: a-frags (8x16B) + residual x (32x4B), all in
    // flight while we stage WuT into LDS.
    bf16x8 a[8];
#pragma unroll
    for (int ks = 0; ks < 4; ++ks)
        a[ks] = *(const bf16x8*)(Xb + (size_t)(rowbase + r) * 128 + ks * 32 + quad * 8);
#pragma unroll
    for (int ks = 4; ks < 8; ++ks)
        a[ks] = *(const bf16x8*)(Agb + (size_t)(rowbase + r) * 128 + (ks - 4) * 32 + quad * 8);

    float xres[8][4];
    const int row0 = rowbase + quad * 4;
#pragma unroll
    for (int reg = 0; reg < 4; ++reg) {
        const int row = min(row0 + reg, NNODES - 1);
#pragma unroll
        for (int ni = 0; ni < 8; ++ni)
            xres[ni][reg] = x[(size_t)row * 128 + ni * 16 + r];
    }

    // Stage WuT -> LDS. Fragment (row, kb) stored at kb ^ (row & 7).
#pragma unroll
    for (int it = 0; it < 16; ++it) {
        int frag = it * 256 + tid;          // [0, 4096)
        int wrow = frag >> 5;
        int kb = frag & 31;
        bf16x8 v = *(const bf16x8*)(WuT + (size_t)wrow * 256 + kb * 8);
        *(bf16x8*)&wut_lds[wrow * 256 + ((kb ^ (wrow & 7)) * 8)] = v;
    }
    __syncthreads();

    f32x4 acc[8];
#pragma unroll
    for (int ni = 0; ni < 8; ++ni) acc[ni] = (f32x4){0.f, 0.f, 0.f, 0.f};

#pragma unroll
    for (int ks = 0; ks < 8; ++ks) {
        const int kb = ks * 4 + quad;
#pragma unroll
        for (int ni = 0; ni < 8; ++ni) {
            const int wrow = ni * 16 + r;
            bf16x8 b = *(const bf16x8*)&wut_lds[wrow * 256 + ((kb ^ (wrow & 7)) * 8)];
            acc[ni] = __builtin_amdgcn_mfma_f32_16x16x32_bf16(a[ks], b, acc[ni], 0, 0, 0);
        }
    }

    float vals[8][4];
    float gcol[8], bcol[8];
#pragma unroll
    for (int ni = 0; ni < 8; ++ni) {
        const int col = ni * 16 + r;
        const float bias = bupd[col];
        gcol[ni] = gamma[col];
        bcol[ni] = beta[col];
#pragma unroll
        for (int reg = 0; reg < 4; ++reg) vals[ni][reg] = acc[ni][reg] + bias;
    }

#pragma unroll
    for (int reg = 0; reg < 4; ++reg) {
        float s = 0.f, s2 = 0.f;
#pragma unroll
        for (int ni = 0; ni < 8; ++ni) {
            s += vals[ni][reg];
            s2 += vals[ni][reg] * vals[ni][reg];
        }
#pragma unroll
        for (int off = 8; off >= 1; off >>= 1) {
            s += __shfl_xor(s, off, 64);
            s2 += __shfl_xor(s2, off, 64);
        }
        const int row = rowbase + quad * 4 + reg;
        if (row < NNODES) {
            const float mu = s * (1.0f / 128.0f);
            const float var = s2 * (1.0f / 128.0f) - mu * mu;
            const float inv = rsqrtf(var + EPS);
#pragma unroll
            for (int ni = 0; ni < 8; ++ni) {
                const int col = ni * 16 + r;
                float hn = (vals[ni][reg] - mu) * inv * gcol[ni] + bcol[ni];
                float ge = 0.5f * hn * (1.0f + erff(hn * 0.70710678118654752f));
                out[(size_t)row * 128 + col] = xres[ni][reg] + ge;
            }
        }
    }
}

// ---------------------------------------------------------------------------
extern "C" void kernel_launch(void* const* d_in, const int* in_sizes, int n_in,
                              void* d_out, int out_size, void* d_ws, size_t ws_size,
                              hipStream_t stream) {
    const float* x     = (const float*)d_in[0];
    const int*   ei    = (const int*)d_in[1];
    const int*   et    = (const int*)d_in[2];
    const float* Wmsg  = (const float*)d_in[3];
    const float* bmsg  = (const float*)d_in[4];
    const float* Wupd  = (const float*)d_in[5];
    const float* bupd  = (const float*)d_in[6];
    const float* gamma = (const float*)d_in[7];
    const float* beta  = (const float*)d_in[8];
    float* out = (float*)d_out;

    char* ws = (char*)d_ws;
    unsigned short* W6T  = (unsigned short*)(ws + OFF_W6T);
    float*          Bv   = (float*)(ws + OFF_BV);
    unsigned short* WuT  = (unsigned short*)(ws + OFF_WUT);
    unsigned short* Xb   = (unsigned short*)(ws + OFF_XB);
    unsigned short* ABb  = (unsigned short*)(ws + OFF_ABB);
    unsigned short* Agb  = (unsigned short*)(ws + OFF_AGB);
    int*            hist = (int*)(ws + OFF_HIST);
    int*            excl = (int*)(ws + OFF_EXCL);
    int*            curs = (int*)(ws + OFF_CURS);
    int*            bsum = (int*)(ws + OFF_BSUM);
    unsigned*       pack = (unsigned*)(ws + OFF_PACK);

    hipMemsetAsync(hist, 0, NNODES * sizeof(int), stream);

    prep_weights<<<515, 256, 0, stream>>>(Wmsg, bmsg, Wupd, W6T, Bv, WuT);
    x_to_bf16<<<(MPAD * 128 / 4 + 255) / 256, 256, 0, stream>>>(x, Xb);
    gemm_ab<<<dim3(MPAD / 64, 3), 256, 0, stream>>>(Xb, W6T, Bv, ABb);
    hist_kernel<<<(NEDGES + 255) / 256, 256, 0, stream>>>(ei, hist);
    scan_phase1<<<NSCAN_BLOCKS, 256, 0, stream>>>(hist, excl, bsum);
    scan_phase3<<<NSCAN_BLOCKS, 256, 0, stream>>>(excl, bsum, curs);
    edge_bucket<<<(NEDGES + 255) / 256, 256, 0, stream>>>(ei, et, curs, pack);
    aggregate<<<(NNODES + 3) / 4, 256, 0, stream>>>(pack, excl, hist, ABb, Agb);
    update_mfma<<<MPAD / 64, 256, 0, stream>>>(Xb, Agb, WuT, x, bupd, gamma, beta, out);
}

// Round 9
// 251.596 us; speedup vs baseline: 3.5619x; 1.0677x over previous
//
#include <hip/hip_runtime.h>
#include <hip/hip_bf16.h>
#include <math.h>

#define HIDDEN 128
#define NNODES 50000
#define NEDGES 600000
#define EPS 1e-5f
#define SCAN_CHUNK 1024
#define NSCAN_BLOCKS ((NNODES + SCAN_CHUNK - 1) / SCAN_CHUNK)  // 49
#define MPAD 50048  // 782 * 64

// phase0 block ranges
#define P0_W6T_END   384
#define P0_BV_END    387
#define P0_WUT_END   515
#define P0_XB_END    (515 + 6256)            // 6771: MPAD*128/4/256 = 6256 blocks
#define P0_HIST_END  (P0_XB_END + 2344)      // 9115: (NEDGES+255)/256 = 2344 blocks

// Workspace layout (bytes), all 16B-aligned
#define OFF_W6T  ((size_t)0)            // 768*128*2   = 196,608
#define OFF_BV   ((size_t)196608)       // 768*4       = 3,072   -> 199,680
#define OFF_WUT  ((size_t)199680)       // 128*256*2   = 65,536  -> 265,216
#define OFF_XB   ((size_t)265216)       // 50048*128*2 = 12,812,288 -> 13,077,504
#define OFF_ABB  ((size_t)13077504)     // 50000*768*2 = 76,800,000 -> 89,877,504
#define OFF_AGB  ((size_t)89877504)     // 50048*128*2 = 12,812,288 -> 102,689,792
#define OFF_HIST ((size_t)102689792)    // pad 200,192 -> 102,889,984
#define OFF_EXCL ((size_t)102889984)    // -> 103,090,176
#define OFF_CURS ((size_t)103090176)    // -> 103,290,368
#define OFF_BSUM ((size_t)103290368)    // 256 -> 103,290,624
#define OFF_PACK ((size_t)103290624)    // 600000*4 = 2,400,000

typedef __attribute__((ext_vector_type(8))) short bf16x8;
typedef __attribute__((ext_vector_type(4))) float f32x4;

__device__ inline unsigned short f2bf(float f) {
    union { float f; unsigned u; } c; c.f = f;
    unsigned u = c.u;
    u += 0x7FFF + ((u >> 16) & 1);  // RNE
    return (unsigned short)(u >> 16);
}
__device__ inline float bf2f(unsigned short h) {
    union { unsigned u; float f; } c; c.u = ((unsigned)h) << 16;
    return c.f;
}
__device__ inline float bflo(unsigned p) { return bf2f((unsigned short)(p & 0xFFFF)); }
__device__ inline float bfhi(unsigned p) { return bf2f((unsigned short)(p >> 16)); }

// ---------------------------------------------------------------------------
// Kernel 0: fused phase-0: weight prep + x->bf16 + dst histogram.
__global__ __launch_bounds__(256) void phase0(const float* __restrict__ Wmsg,
                                              const float* __restrict__ bmsg,
                                              const float* __restrict__ Wupd,
                                              const float* __restrict__ x,
                                              const int* __restrict__ ei,
                                              unsigned short* __restrict__ W6T,
                                              float* __restrict__ Bv,
                                              unsigned short* __restrict__ WuT,
                                              unsigned short* __restrict__ Xb,
                                              int* __restrict__ hist) {
    const int b = blockIdx.x;
    const int tid = threadIdx.x;
    if (b < P0_W6T_END) {
        int idx = b * 256 + tid;
        int col = idx >> 7;
        int k = idx & 127;
        int half = col >= 384;
        int rem = col - half * 384;
        int t = rem >> 7;
        int h = rem & 127;
        W6T[idx] = f2bf(Wmsg[t * 32768 + (half * 128 + k) * 128 + h]);
    } else if (b < P0_BV_END) {
        int idx = (b - P0_W6T_END) * 256 + tid;
        if (idx < 768) Bv[idx] = (idx < 384) ? 0.f : bmsg[idx - 384];
    } else if (b < P0_WUT_END) {
        int idx = (b - P0_BV_END) * 256 + tid;
        int n = idx >> 8;
        int k = idx & 255;
        WuT[idx] = f2bf(Wupd[(size_t)k * 128 + n]);
    } else if (b < P0_XB_END) {
        int i = (b - P0_WUT_END) * 256 + tid;   // group of 4 elements
        int base = i * 4;
        if (base < MPAD * 128) {
            ushort4 o;
            if (base < NNODES * 128) {
                float4 v = *(const float4*)(x + base);
                o.x = f2bf(v.x); o.y = f2bf(v.y); o.z = f2bf(v.z); o.w = f2bf(v.w);
            } else {
                o.x = o.y = o.z = o.w = 0;
            }
            *(ushort4*)(Xb + base) = o;
        }
    } else {
        int e = (b - P0_XB_END) * 256 + tid;
        if (e < NEDGES) atomicAdd(&hist[ei[NEDGES + e]], 1);
    }
}

// ---------------------------------------------------------------------------
// Kernel 2: MFMA GEMM: ABb[50000][768] bf16 = Xb @ W6T^T + Bv
// Block = 4 waves = 64 rows x 256 cols; grid (782, 3).
// Xb tile staged in LDS (XOR-swizzled); W6T frags hoisted to regs; LDS buffer
// reused for the coalesced output tile.
__global__ __launch_bounds__(256) void gemm_ab(const unsigned short* __restrict__ Xb,
                                               const unsigned short* __restrict__ W6T,
                                               const float* __restrict__ Bv,
                                               unsigned short* __restrict__ ABb) {
    __shared__ unsigned short lds_buf[64 * 264];  // 33 KB: xs view then tile view
    const int tid = threadIdx.x;
    const int mbase = blockIdx.x * 64;
    const int w = tid >> 6;
    const int nbase = blockIdx.y * 256 + w * 64;
    const int lane = tid & 63;
    const int r = lane & 15;
    const int quad = lane >> 4;

    // Hoisted W6T b-frags (L2-hot, in flight during staging/barriers)
    bf16x8 b[4][4];  // [ks][ni]
#pragma unroll
    for (int ks = 0; ks < 4; ++ks)
#pragma unroll
        for (int ni = 0; ni < 4; ++ni)
            b[ks][ni] = *(const bf16x8*)(W6T + (size_t)(nbase + ni * 16 + r) * 128 + ks * 32 + quad * 8);

    // Stage Xb tile (64 rows x 128 u16) into LDS, swizzled: frag (row,kb) at kb^(row&7)
#pragma unroll
    for (int i = 0; i < 4; ++i) {
        int item = i * 256 + tid;          // [0,1024)
        int row = item >> 4;
        int kb = item & 15;
        bf16x8 v = *(const bf16x8*)(Xb + (size_t)(mbase + row) * 128 + kb * 8);
        *(bf16x8*)&lds_buf[row * 128 + ((kb ^ (row & 7)) * 8)] = v;
    }
    __syncthreads();

    f32x4 acc[4][4];
#pragma unroll
    for (int mi = 0; mi < 4; ++mi)
#pragma unroll
        for (int ni = 0; ni < 4; ++ni) acc[mi][ni] = (f32x4){0.f, 0.f, 0.f, 0.f};

#pragma unroll
    for (int ks = 0; ks < 4; ++ks) {
        bf16x8 a[4];
        const int kb = ks * 4 + quad;
#pragma unroll
        for (int mi = 0; mi < 4; ++mi)
            a[mi] = *(const bf16x8*)&lds_buf[(mi * 16 + r) * 128 + ((kb ^ (r & 7)) * 8)];
#pragma unroll
        for (int mi = 0; mi < 4; ++mi)
#pragma unroll
            for (int ni = 0; ni < 4; ++ni)
                acc[mi][ni] = __builtin_amdgcn_mfma_f32_16x16x32_bf16(a[mi], b[ks][ni], acc[mi][ni], 0, 0, 0);
    }

    __syncthreads();  // all xs reads done before reusing lds_buf as output tile
    unsigned short (*tile)[264] = (unsigned short(*)[264])lds_buf;

#pragma unroll
    for (int ni = 0; ni < 4; ++ni) {
        const int col_l = w * 64 + ni * 16 + r;
        const float bias = Bv[blockIdx.y * 256 + col_l];
#pragma unroll
        for (int mi = 0; mi < 4; ++mi) {
            f32x4 v = acc[mi][ni];
#pragma unroll
            for (int reg = 0; reg < 4; ++reg) {
                tile[mi * 16 + quad * 4 + reg][col_l] = f2bf(v[reg] + bias);
            }
        }
    }
    __syncthreads();

#pragma unroll
    for (int i = 0; i < 8; ++i) {
        int item = i * 256 + tid;
        int row_l = item >> 5;
        int chunk = item & 31;
        int grow = mbase + row_l;
        if (grow < NNODES) {
            bf16x8 v = *(const bf16x8*)&tile[row_l][chunk * 8];
            *(bf16x8*)(ABb + (size_t)grow * 768 + blockIdx.y * 256 + chunk * 8) = v;
        }
    }
}

// ---------------------------------------------------------------------------
// CSR build
__global__ __launch_bounds__(256) void scan_phase1(const int* __restrict__ hist,
                                                   int* __restrict__ excl,
                                                   int* __restrict__ blockSums) {
    __shared__ int lds[256];
    const int blk = blockIdx.x;
    const int t = threadIdx.x;
    const int base = blk * SCAN_CHUNK + t * 4;
    int v[4];
    int s = 0;
#pragma unroll
    for (int i = 0; i < 4; ++i) {
        v[i] = (base + i < NNODES) ? hist[base + i] : 0;
        s += v[i];
    }
    lds[t] = s;
    __syncthreads();
    for (int off = 1; off < 256; off <<= 1) {
        int add = (t >= off) ? lds[t - off] : 0;
        __syncthreads();
        lds[t] += add;
        __syncthreads();
    }
    int incl = lds[t];
    int run = incl - s;
#pragma unroll
    for (int i = 0; i < 4; ++i) {
        if (base + i < NNODES) excl[base + i] = run;
        run += v[i];
    }
    if (t == 255) blockSums[blk] = incl;
}

__global__ __launch_bounds__(256) void scan_phase3(int* __restrict__ excl,
                                                   const int* __restrict__ blockSums,
                                                   int* __restrict__ cursor) {
    __shared__ int s_add;
    const int blk = blockIdx.x;
    const int t = threadIdx.x;
    if (t < 64) {
        int v = (t < blk) ? blockSums[t] : 0;
#pragma unroll
        for (int off = 32; off >= 1; off >>= 1) v += __shfl_xor(v, off, 64);
        if (t == 0) s_add = v;
    }
    __syncthreads();
    const int add = s_add;
    for (int i = t; i < SCAN_CHUNK; i += 256) {
        int idx = blk * SCAN_CHUNK + i;
        if (idx < NNODES) {
            int o = excl[idx] + add;
            excl[idx] = o;
            cursor[idx] = o;
        }
    }
}

__global__ __launch_bounds__(256) void edge_bucket(const int* __restrict__ ei,
                                                   const int* __restrict__ et,
                                                   int* __restrict__ cursor,
                                                   unsigned* __restrict__ packed) {
    int e = blockIdx.x * 256 + threadIdx.x;
    if (e >= NEDGES) return;
    int src = ei[e];
    int dst = ei[NEDGES + e];
    int t = et[e];
    int pos = atomicAdd(&cursor[dst], 1);
    packed[pos] = (unsigned)(src * 384 + t * 64) | ((unsigned)t << 25);
}

// ---------------------------------------------------------------------------
// Kernel 4: gather aggregation -> normalized bf16 agg. One wave per node.
__global__ __launch_bounds__(256) void aggregate(const unsigned* __restrict__ packed,
                                                 const int* __restrict__ excl,
                                                 const int* __restrict__ hist,
                                                 const unsigned short* __restrict__ ABb,
                                                 unsigned short* __restrict__ Agb) {
    const int n = blockIdx.x * 4 + (threadIdx.x >> 6);
    const int lane = threadIdx.x & 63;
    if (n >= NNODES) return;
    const int start = excl[n];
    const int deg = hist[n];
    const unsigned* ABu = (const unsigned*)ABb;

    float ax = 0.f, ay = 0.f;
    int c1 = 0, c2 = 0;

    for (int base = 0; base < deg; base += 64) {
        const int m = min(64, deg - base);
        unsigned v = 0;
        if (lane < m) v = packed[start + base + lane];
        int j = 0;
        for (; j + 4 <= m; j += 4) {
            unsigned v0 = __shfl(v, j, 64);
            unsigned v1 = __shfl(v, j + 1, 64);
            unsigned v2 = __shfl(v, j + 2, 64);
            unsigned v3 = __shfl(v, j + 3, 64);
            unsigned p0 = ABu[(v0 & 0x1FFFFFF) + lane];
            unsigned p1 = ABu[(v1 & 0x1FFFFFF) + lane];
            unsigned p2 = ABu[(v2 & 0x1FFFFFF) + lane];
            unsigned p3 = ABu[(v3 & 0x1FFFFFF) + lane];
            int t0 = v0 >> 25, t1 = v1 >> 25, t2 = v2 >> 25, t3 = v3 >> 25;
            c1 += (t0 == 1) + (t1 == 1) + (t2 == 1) + (t3 == 1);
            c2 += (t0 == 2) + (t1 == 2) + (t2 == 2) + (t3 == 2);
            ax += (bflo(p0) + bflo(p1)) + (bflo(p2) + bflo(p3));
            ay += (bfhi(p0) + bfhi(p1)) + (bfhi(p2) + bfhi(p3));
        }
        for (; j < m; ++j) {
            unsigned v0 = __shfl(v, j, 64);
            unsigned p0 = ABu[(v0 & 0x1FFFFFF) + lane];
            int t0 = v0 >> 25;
            c1 += (t0 == 1);
            c2 += (t0 == 2);
            ax += bflo(p0);
            ay += bfhi(p0);
        }
    }

    const int c0 = deg - c1 - c2;
    const unsigned* browbase = ABu + (size_t)n * 384 + 192;
    if (c0) {
        unsigned p = browbase[lane];
        ax += c0 * bflo(p); ay += c0 * bfhi(p);
    }
    if (c1) {
        unsigned p = browbase[64 + lane];
        ax += c1 * bflo(p); ay += c1 * bfhi(p);
    }
    if (c2) {
        unsigned p = browbase[128 + lane];
        ax += c2 * bflo(p); ay += c2 * bfhi(p);
    }

    const float inv = 1.0f / fmaxf((float)deg, 1.0f);
    unsigned packed_out = (unsigned)f2bf(ax * inv) | ((unsigned)f2bf(ay * inv) << 16);
    ((unsigned*)(Agb + (size_t)n * 128))[lane] = packed_out;
}

// ---------------------------------------------------------------------------
// Kernel 5: MFMA update with LDS-staged WuT (XOR-swizzled, 64 KB).
__global__ __launch_bounds__(256) void update_mfma(const unsigned short* __restrict__ Xb,
                                                   const unsigned short* __restrict__ Agb,
                                                   const unsigned short* __restrict__ WuT,
                                                   const float* __restrict__ x,
                                                   const float* __restrict__ bupd,
                                                   const float* __restrict__ gamma,
                                                   const float* __restrict__ beta,
                                                   float* __restrict__ out) {
    __shared__ unsigned short wut_lds[128 * 256];  // 64 KB, swizzled

    const int tid = threadIdx.x;
    const int rowbase = blockIdx.x * 64 + (tid >> 6) * 16;
    const int lane = tid & 63;
    const int r = lane & 15;
    const int quad = lane >> 4;

    bf16x8 a[8];
#pragma unroll
    for (int ks = 0; ks < 4; ++ks)
        a[ks] = *(const bf16x8*)(Xb + (size_t)(rowbase + r) * 128 + ks * 32 + quad * 8);
#pragma unroll
    for (int ks = 4; ks < 8; ++ks)
        a[ks] = *(const bf16x8*)(Agb + (size_t)(rowbase + r) * 128 + (ks - 4) * 32 + quad * 8);

    float xres[8][4];
    const int row0 = rowbase + quad * 4;
#pragma unroll
    for (int reg = 0; reg < 4; ++reg) {
        const int row = min(row0 + reg, NNODES - 1);
#pragma unroll
        for (int ni = 0; ni < 8; ++ni)
            xres[ni][reg] = x[(size_t)row * 128 + ni * 16 + r];
    }

#pragma unroll
    for (int it = 0; it < 16; ++it) {
        int frag = it * 256 + tid;
        int wrow = frag >> 5;
        int kb = frag & 31;
        bf16x8 v = *(const bf16x8*)(WuT + (size_t)wrow * 256 + kb * 8);
        *(bf16x8*)&wut_lds[wrow * 256 + ((kb ^ (wrow & 7)) * 8)] = v;
    }
    __syncthreads();

    f32x4 acc[8];
#pragma unroll
    for (int ni = 0; ni < 8; ++ni) acc[ni] = (f32x4){0.f, 0.f, 0.f, 0.f};

#pragma unroll
    for (int ks = 0; ks < 8; ++ks) {
        const int kb = ks * 4 + quad;
#pragma unroll
        for (int ni = 0; ni < 8; ++ni) {
            const int wrow = ni * 16 + r;
            bf16x8 b = *(const bf16x8*)&wut_lds[wrow * 256 + ((kb ^ (wrow & 7)) * 8)];
            acc[ni] = __builtin_amdgcn_mfma_f32_16x16x32_bf16(a[ks], b, acc[ni], 0, 0, 0);
        }
    }

    float vals[8][4];
    float gcol[8], bcol[8];
#pragma unroll
    for (int ni = 0; ni < 8; ++ni) {
        const int col = ni * 16 + r;
        const float bias = bupd[col];
        gcol[ni] = gamma[col];
        bcol[ni] = beta[col];
#pragma unroll
        for (int reg = 0; reg < 4; ++reg) vals[ni][reg] = acc[ni][reg] + bias;
    }

#pragma unroll
    for (int reg = 0; reg < 4; ++reg) {
        float s = 0.f, s2 = 0.f;
#pragma unroll
        for (int ni = 0; ni < 8; ++ni) {
            s += vals[ni][reg];
            s2 += vals[ni][reg] * vals[ni][reg];
        }
#pragma unroll
        for (int off = 8; off >= 1; off >>= 1) {
            s += __shfl_xor(s, off, 64);
            s2 += __shfl_xor(s2, off, 64);
        }
        const int row = rowbase + quad * 4 + reg;
        if (row < NNODES) {
            const float mu = s * (1.0f / 128.0f);
            const float var = s2 * (1.0f / 128.0f) - mu * mu;
            const float inv = rsqrtf(var + EPS);
#pragma unroll
            for (int ni = 0; ni < 8; ++ni) {
                const int col = ni * 16 + r;
                float hn = (vals[ni][reg] - mu) * inv * gcol[ni] + bcol[ni];
                float ge = 0.5f * hn * (1.0f + erff(hn * 0.70710678118654752f));
                out[(size_t)row * 128 + col] = xres[ni][reg] + ge;
            }
        }
    }
}

// ---------------------------------------------------------------------------
extern "C" void kernel_launch(void* const* d_in, const int* in_sizes, int n_in,
                              void* d_out, int out_size, void* d_ws, size_t ws_size,
                              hipStream_t stream) {
    const float* x     = (const float*)d_in[0];
    const int*   ei    = (const int*)d_in[1];
    const int*   et    = (const int*)d_in[2];
    const float* Wmsg  = (const float*)d_in[3];
    const float* bmsg  = (const float*)d_in[4];
    const float* Wupd  = (const float*)d_in[5];
    const float* bupd  = (const float*)d_in[6];
    const float* gamma = (const float*)d_in[7];
    const float* beta  = (const float*)d_in[8];
    float* out = (float*)d_out;

    char* ws = (char*)d_ws;
    unsigned short* W6T  = (unsigned short*)(ws + OFF_W6T);
    float*          Bv   = (float*)(ws + OFF_BV);
    unsigned short* WuT  = (unsigned short*)(ws + OFF_WUT);
    unsigned short* Xb   = (unsigned short*)(ws + OFF_XB);
    unsigned short* ABb  = (unsigned short*)(ws + OFF_ABB);
    unsigned short* Agb  = (unsigned short*)(ws + OFF_AGB);
    int*            hist = (int*)(ws + OFF_HIST);
    int*            excl = (int*)(ws + OFF_EXCL);
    int*            curs = (int*)(ws + OFF_CURS);
    int*            bsum = (int*)(ws + OFF_BSUM);
    unsigned*       pack = (unsigned*)(ws + OFF_PACK);

    hipMemsetAsync(hist, 0, NNODES * sizeof(int), stream);

    phase0<<<P0_HIST_END, 256, 0, stream>>>(Wmsg, bmsg, Wupd, x, ei, W6T, Bv, WuT, Xb, hist);
    gemm_ab<<<dim3(MPAD / 64, 3), 256, 0, stream>>>(Xb, W6T, Bv, ABb);
    scan_phase1<<<NSCAN_BLOCKS, 256, 0, stream>>>(hist, excl, bsum);
    scan_phase3<<<NSCAN_BLOCKS, 256, 0, stream>>>(excl, bsum, curs);
    edge_bucket<<<(NEDGES + 255) / 256, 256, 0, stream>>>(ei, et, curs, pack);
    aggregate<<<(NNODES + 3) / 4, 256, 0, stream>>>(pack, excl, hist, ABb, Agb);
    update_mfma<<<MPAD / 64, 256, 0, stream>>>(Xb, Agb, WuT, x, bupd, gamma, beta, out);
}

// Round 10
// 249.617 us; speedup vs baseline: 3.5901x; 1.0079x over previous
//
#include <hip/hip_runtime.h>
#include <hip/hip_bf16.h>
#include <math.h>

#define HIDDEN 128
#define NNODES 50000
#define NEDGES 600000
#define EPS 1e-5f
#define SCAN_CHUNK 1024
#define NSCAN_BLOCKS ((NNODES + SCAN_CHUNK - 1) / SCAN_CHUNK)  // 49
#define MPAD 50048  // 782 * 64

// phase0 block ranges
#define P0_W6T_END   384
#define P0_BV_END    387
#define P0_WUT_END   515
#define P0_XB_END    (515 + 6256)            // MPAD*128/4/256 = 6256 blocks
#define P0_HIST_END  (P0_XB_END + 2344)      // (NEDGES+255)/256 = 2344 blocks

// Workspace layout (bytes), all 16B-aligned
#define OFF_W6T  ((size_t)0)            // 768*128*2   = 196,608
#define OFF_BV   ((size_t)196608)       // 768*4       = 3,072   -> 199,680
#define OFF_WUT  ((size_t)199680)       // 128*256*2   = 65,536  -> 265,216
#define OFF_XB   ((size_t)265216)       // 50048*128*2 = 12,812,288 -> 13,077,504
#define OFF_ABB  ((size_t)13077504)     // 50000*768*2 = 76,800,000 -> 89,877,504
#define OFF_AGB  ((size_t)89877504)     // 50048*128*2 = 12,812,288 -> 102,689,792
#define OFF_HIST ((size_t)102689792)    // pad 200,192 -> 102,889,984
#define OFF_EXCL ((size_t)102889984)    // -> 103,090,176
#define OFF_CURS ((size_t)103090176)    // -> 103,290,368
#define OFF_BSUM ((size_t)103290368)    // 256 -> 103,290,624
#define OFF_PACK ((size_t)103290624)    // 600000*4 = 2,400,000

typedef __attribute__((ext_vector_type(8))) short bf16x8;
typedef __attribute__((ext_vector_type(4))) float f32x4;

__device__ inline unsigned short f2bf(float f) {
    union { float f; unsigned u; } c; c.f = f;
    unsigned u = c.u;
    u += 0x7FFF + ((u >> 16) & 1);  // RNE
    return (unsigned short)(u >> 16);
}
__device__ inline float bf2f(unsigned short h) {
    union { unsigned u; float f; } c; c.u = ((unsigned)h) << 16;
    return c.f;
}
__device__ inline float bflo(unsigned p) { return bf2f((unsigned short)(p & 0xFFFF)); }
__device__ inline float bfhi(unsigned p) { return bf2f((unsigned short)(p >> 16)); }

// ---------------------------------------------------------------------------
// Kernel 0: fused phase-0: weight prep + x->bf16 + dst histogram.
__global__ __launch_bounds__(256) void phase0(const float* __restrict__ Wmsg,
                                              const float* __restrict__ bmsg,
                                              const float* __restrict__ Wupd,
                                              const float* __restrict__ x,
                                              const int* __restrict__ ei,
                                              unsigned short* __restrict__ W6T,
                                              float* __restrict__ Bv,
                                              unsigned short* __restrict__ WuT,
                                              unsigned short* __restrict__ Xb,
                                              int* __restrict__ hist) {
    const int b = blockIdx.x;
    const int tid = threadIdx.x;
    if (b < P0_W6T_END) {
        int idx = b * 256 + tid;
        int col = idx >> 7;
        int k = idx & 127;
        int half = col >= 384;
        int rem = col - half * 384;
        int t = rem >> 7;
        int h = rem & 127;
        W6T[idx] = f2bf(Wmsg[t * 32768 + (half * 128 + k) * 128 + h]);
    } else if (b < P0_BV_END) {
        int idx = (b - P0_W6T_END) * 256 + tid;
        if (idx < 768) Bv[idx] = (idx < 384) ? 0.f : bmsg[idx - 384];
    } else if (b < P0_WUT_END) {
        int idx = (b - P0_BV_END) * 256 + tid;
        int n = idx >> 8;
        int k = idx & 255;
        WuT[idx] = f2bf(Wupd[(size_t)k * 128 + n]);
    } else if (b < P0_XB_END) {
        int i = (b - P0_WUT_END) * 256 + tid;
        int base = i * 4;
        if (base < MPAD * 128) {
            ushort4 o;
            if (base < NNODES * 128) {
                float4 v = *(const float4*)(x + base);
                o.x = f2bf(v.x); o.y = f2bf(v.y); o.z = f2bf(v.z); o.w = f2bf(v.w);
            } else {
                o.x = o.y = o.z = o.w = 0;
            }
            *(ushort4*)(Xb + base) = o;
        }
    } else {
        int e = (b - P0_XB_END) * 256 + tid;
        if (e < NEDGES) atomicAdd(&hist[ei[NEDGES + e]], 1);
    }
}

// ---------------------------------------------------------------------------
// Kernel 2: MFMA GEMM: ABb[50000][768] bf16 = Xb @ W6T^T + Bv
__global__ __launch_bounds__(256) void gemm_ab(const unsigned short* __restrict__ Xb,
                                               const unsigned short* __restrict__ W6T,
                                               const float* __restrict__ Bv,
                                               unsigned short* __restrict__ ABb) {
    __shared__ unsigned short lds_buf[64 * 264];  // 33 KB: xs view then tile view
    const int tid = threadIdx.x;
    const int mbase = blockIdx.x * 64;
    const int w = tid >> 6;
    const int nbase = blockIdx.y * 256 + w * 64;
    const int lane = tid & 63;
    const int r = lane & 15;
    const int quad = lane >> 4;

    // Hoisted W6T b-frags (L2-hot, in flight during staging/barriers)
    bf16x8 b[4][4];  // [ks][ni]
#pragma unroll
    for (int ks = 0; ks < 4; ++ks)
#pragma unroll
        for (int ni = 0; ni < 4; ++ni)
            b[ks][ni] = *(const bf16x8*)(W6T + (size_t)(nbase + ni * 16 + r) * 128 + ks * 32 + quad * 8);

    // Stage Xb tile (64 rows x 128 u16) into LDS, swizzled: frag (row,kb) at kb^(row&7)
#pragma unroll
    for (int i = 0; i < 4; ++i) {
        int item = i * 256 + tid;
        int row = item >> 4;
        int kb = item & 15;
        bf16x8 v = *(const bf16x8*)(Xb + (size_t)(mbase + row) * 128 + kb * 8);
        *(bf16x8*)&lds_buf[row * 128 + ((kb ^ (row & 7)) * 8)] = v;
    }
    __syncthreads();

    f32x4 acc[4][4];
#pragma unroll
    for (int mi = 0; mi < 4; ++mi)
#pragma unroll
        for (int ni = 0; ni < 4; ++ni) acc[mi][ni] = (f32x4){0.f, 0.f, 0.f, 0.f};

#pragma unroll
    for (int ks = 0; ks < 4; ++ks) {
        bf16x8 a[4];
        const int kb = ks * 4 + quad;
#pragma unroll
        for (int mi = 0; mi < 4; ++mi)
            a[mi] = *(const bf16x8*)&lds_buf[(mi * 16 + r) * 128 + ((kb ^ (r & 7)) * 8)];
#pragma unroll
        for (int mi = 0; mi < 4; ++mi)
#pragma unroll
            for (int ni = 0; ni < 4; ++ni)
                acc[mi][ni] = __builtin_amdgcn_mfma_f32_16x16x32_bf16(a[mi], b[ks][ni], acc[mi][ni], 0, 0, 0);
    }

    __syncthreads();
    unsigned short (*tile)[264] = (unsigned short(*)[264])lds_buf;

#pragma unroll
    for (int ni = 0; ni < 4; ++ni) {
        const int col_l = w * 64 + ni * 16 + r;
        const float bias = Bv[blockIdx.y * 256 + col_l];
#pragma unroll
        for (int mi = 0; mi < 4; ++mi) {
            f32x4 v = acc[mi][ni];
#pragma unroll
            for (int reg = 0; reg < 4; ++reg) {
                tile[mi * 16 + quad * 4 + reg][col_l] = f2bf(v[reg] + bias);
            }
        }
    }
    __syncthreads();

#pragma unroll
    for (int i = 0; i < 8; ++i) {
        int item = i * 256 + tid;
        int row_l = item >> 5;
        int chunk = item & 31;
        int grow = mbase + row_l;
        if (grow < NNODES) {
            bf16x8 v = *(const bf16x8*)&tile[row_l][chunk * 8];
            *(bf16x8*)(ABb + (size_t)grow * 768 + blockIdx.y * 256 + chunk * 8) = v;
        }
    }
}

// ---------------------------------------------------------------------------
// CSR build
__global__ __launch_bounds__(256) void scan_phase1(const int* __restrict__ hist,
                                                   int* __restrict__ excl,
                                                   int* __restrict__ blockSums) {
    __shared__ int lds[256];
    const int blk = blockIdx.x;
    const int t = threadIdx.x;
    const int base = blk * SCAN_CHUNK + t * 4;
    int v[4];
    int s = 0;
#pragma unroll
    for (int i = 0; i < 4; ++i) {
        v[i] = (base + i < NNODES) ? hist[base + i] : 0;
        s += v[i];
    }
    lds[t] = s;
    __syncthreads();
    for (int off = 1; off < 256; off <<= 1) {
        int add = (t >= off) ? lds[t - off] : 0;
        __syncthreads();
        lds[t] += add;
        __syncthreads();
    }
    int incl = lds[t];
    int run = incl - s;
#pragma unroll
    for (int i = 0; i < 4; ++i) {
        if (base + i < NNODES) excl[base + i] = run;
        run += v[i];
    }
    if (t == 255) blockSums[blk] = incl;
}

__global__ __launch_bounds__(256) void scan_phase3(int* __restrict__ excl,
                                                   const int* __restrict__ blockSums,
                                                   int* __restrict__ cursor) {
    __shared__ int s_add;
    const int blk = blockIdx.x;
    const int t = threadIdx.x;
    if (t < 64) {
        int v = (t < blk) ? blockSums[t] : 0;
#pragma unroll
        for (int off = 32; off >= 1; off >>= 1) v += __shfl_xor(v, off, 64);
        if (t == 0) s_add = v;
    }
    __syncthreads();
    const int add = s_add;
    for (int i = t; i < SCAN_CHUNK; i += 256) {
        int idx = blk * SCAN_CHUNK + i;
        if (idx < NNODES) {
            int o = excl[idx] + add;
            excl[idx] = o;
            cursor[idx] = o;
        }
    }
}

__global__ __launch_bounds__(256) void edge_bucket(const int* __restrict__ ei,
                                                   const int* __restrict__ et,
                                                   int* __restrict__ cursor,
                                                   unsigned* __restrict__ packed) {
    int e = blockIdx.x * 256 + threadIdx.x;
    if (e >= NEDGES) return;
    int src = ei[e];
    int dst = ei[NEDGES + e];
    int t = et[e];
    int pos = atomicAdd(&cursor[dst], 1);
    packed[pos] = (unsigned)(src * 384 + t * 64) | ((unsigned)t << 25);
}

// ---------------------------------------------------------------------------
// Kernel 4: gather aggregation -> normalized bf16 agg. One wave per node.
// Paired-edge scheme: lanes 0-31 process even edges, 32-63 odd edges; each
// lane loads 8B (uint2 = 4 bf16 cols) per edge -> 2 edges in flight per load,
// 8 edges per unrolled iteration. Halves combined via shfl_xor(32).
__global__ __launch_bounds__(256) void aggregate(const unsigned* __restrict__ packed,
                                                 const int* __restrict__ excl,
                                                 const int* __restrict__ hist,
                                                 const unsigned short* __restrict__ ABb,
                                                 unsigned short* __restrict__ Agb) {
    const int n = blockIdx.x * 4 + (threadIdx.x >> 6);
    const int lane = threadIdx.x & 63;
    if (n >= NNODES) return;
    const int start = excl[n];
    const int deg = hist[n];
    const uint2* AB2 = (const uint2*)ABb;

    const int half = lane >> 5;   // which edge of the pair
    const int cl = lane & 31;     // column chunk: cols 4*cl .. 4*cl+3

    float s0 = 0.f, s1 = 0.f, s2 = 0.f, s3 = 0.f;
    int c1 = 0, c2 = 0;

    for (int base = 0; base < deg; base += 64) {
        const int m = min(64, deg - base);
        unsigned v = 0;
        if (lane < m) v = packed[start + base + lane];
        int j = 0;
        // 4 pairs (8 edges) per iteration: 4 independent 8B loads per lane
        for (; j + 8 <= m; j += 8) {
            unsigned e0 = __shfl(v, j + 0 + half, 64);
            unsigned e1 = __shfl(v, j + 2 + half, 64);
            unsigned e2 = __shfl(v, j + 4 + half, 64);
            unsigned e3 = __shfl(v, j + 6 + half, 64);
            uint2 q0 = AB2[((e0 & 0x1FFFFFF) >> 1) + cl];
            uint2 q1 = AB2[((e1 & 0x1FFFFFF) >> 1) + cl];
            uint2 q2 = AB2[((e2 & 0x1FFFFFF) >> 1) + cl];
            uint2 q3 = AB2[((e3 & 0x1FFFFFF) >> 1) + cl];
            int t0 = e0 >> 25, t1 = e1 >> 25, t2 = e2 >> 25, t3 = e3 >> 25;
            c1 += (t0 == 1) + (t1 == 1) + (t2 == 1) + (t3 == 1);
            c2 += (t0 == 2) + (t1 == 2) + (t2 == 2) + (t3 == 2);
            s0 += (bflo(q0.x) + bflo(q1.x)) + (bflo(q2.x) + bflo(q3.x));
            s1 += (bfhi(q0.x) + bfhi(q1.x)) + (bfhi(q2.x) + bfhi(q3.x));
            s2 += (bflo(q0.y) + bflo(q1.y)) + (bflo(q2.y) + bflo(q3.y));
            s3 += (bfhi(q0.y) + bfhi(q1.y)) + (bfhi(q2.y) + bfhi(q3.y));
        }
        for (; j + 2 <= m; j += 2) {
            unsigned e0 = __shfl(v, j + half, 64);
            uint2 q0 = AB2[((e0 & 0x1FFFFFF) >> 1) + cl];
            int t0 = e0 >> 25;
            c1 += (t0 == 1);
            c2 += (t0 == 2);
            s0 += bflo(q0.x); s1 += bfhi(q0.x);
            s2 += bflo(q0.y); s3 += bfhi(q0.y);
        }
        if (j < m) {  // odd leftover edge: only half 0 contributes
            unsigned e0 = __shfl(v, j, 64);
            if (half == 0) {
                uint2 q0 = AB2[((e0 & 0x1FFFFFF) >> 1) + cl];
                int t0 = e0 >> 25;
                c1 += (t0 == 1);
                c2 += (t0 == 2);
                s0 += bflo(q0.x); s1 += bfhi(q0.x);
                s2 += bflo(q0.y); s3 += bfhi(q0.y);
            }
        }
    }

    // combine the two halves
    s0 += __shfl_xor(s0, 32, 64);
    s1 += __shfl_xor(s1, 32, 64);
    s2 += __shfl_xor(s2, 32, 64);
    s3 += __shfl_xor(s3, 32, 64);
    c1 += __shfl_xor(c1, 32, 64);
    c2 += __shfl_xor(c2, 32, 64);
    const int c0 = deg - c1 - c2;

    // B-half contributions: rows at uint2 offsets n*192+96 (+32 per type)
    const uint2* brow = AB2 + (size_t)n * 192 + 96;
    if (c0) {
        uint2 p = brow[cl];
        s0 += c0 * bflo(p.x); s1 += c0 * bfhi(p.x);
        s2 += c0 * bflo(p.y); s3 += c0 * bfhi(p.y);
    }
    if (c1) {
        uint2 p = brow[32 + cl];
        s0 += c1 * bflo(p.x); s1 += c1 * bfhi(p.x);
        s2 += c1 * bflo(p.y); s3 += c1 * bfhi(p.y);
    }
    if (c2) {
        uint2 p = brow[64 + cl];
        s0 += c2 * bflo(p.x); s1 += c2 * bfhi(p.x);
        s2 += c2 * bflo(p.y); s3 += c2 * bfhi(p.y);
    }

    const float inv = 1.0f / fmaxf((float)deg, 1.0f);
    if (half == 0) {
        uint2 o;
        o.x = (unsigned)f2bf(s0 * inv) | ((unsigned)f2bf(s1 * inv) << 16);
        o.y = (unsigned)f2bf(s2 * inv) | ((unsigned)f2bf(s3 * inv) << 16);
        ((uint2*)(Agb + (size_t)n * 128))[cl] = o;
    }
}

// ---------------------------------------------------------------------------
// Kernel 5: MFMA update with LDS-staged WuT. Residual x reconstructed from the
// already-loaded Xb A-frags via identity-MFMA (A-layout -> C-layout), so no
// scattered fp32 x loads at all.
__global__ __launch_bounds__(256) void update_mfma(const unsigned short* __restrict__ Xb,
                                                   const unsigned short* __restrict__ Agb,
                                                   const unsigned short* __restrict__ WuT,
                                                   const float* __restrict__ bupd,
                                                   const float* __restrict__ gamma,
                                                   const float* __restrict__ beta,
                                                   float* __restrict__ out) {
    __shared__ unsigned short wut_lds[128 * 256];  // 64 KB, swizzled

    const int tid = threadIdx.x;
    const int rowbase = blockIdx.x * 64 + (tid >> 6) * 16;
    const int lane = tid & 63;
    const int r = lane & 15;
    const int quad = lane >> 4;

    bf16x8 a[8];
#pragma unroll
    for (int ks = 0; ks < 4; ++ks)
        a[ks] = *(const bf16x8*)(Xb + (size_t)(rowbase + r) * 128 + ks * 32 + quad * 8);
#pragma unroll
    for (int ks = 4; ks < 8; ++ks)
        a[ks] = *(const bf16x8*)(Agb + (size_t)(rowbase + r) * 128 + (ks - 4) * 32 + quad * 8);

#pragma unroll
    for (int it = 0; it < 16; ++it) {
        int frag = it * 256 + tid;
        int wrow = frag >> 5;
        int kb = frag & 31;
        bf16x8 v = *(const bf16x8*)(WuT + (size_t)wrow * 256 + kb * 8);
        *(bf16x8*)&wut_lds[wrow * 256 + ((kb ^ (wrow & 7)) * 8)] = v;
    }

    // One-hot B-frags for identity extraction (o = 0 and o = 16):
    // E[n=r][k_local=quad*8+t] = 1 iff quad*8+t == o+r
    bf16x8 e0, e1;
    const int tgt0 = r;
    const int tgt1 = 16 + r;
#pragma unroll
    for (int t = 0; t < 8; ++t) {
        e0[t] = (short)((quad * 8 + t == tgt0) ? 0x3F80 : 0);
        e1[t] = (short)((quad * 8 + t == tgt1) ? 0x3F80 : 0);
    }
    // xres[ni] in C-layout: row = rowbase+quad*4+reg, col = ni*16+r
    f32x4 xr[8];
#pragma unroll
    for (int ni = 0; ni < 8; ++ni) {
        f32x4 z = (f32x4){0.f, 0.f, 0.f, 0.f};
        xr[ni] = __builtin_amdgcn_mfma_f32_16x16x32_bf16(a[ni >> 1], (ni & 1) ? e1 : e0, z, 0, 0, 0);
    }

    __syncthreads();

    f32x4 acc[8];
#pragma unroll
    for (int ni = 0; ni < 8; ++ni) acc[ni] = (f32x4){0.f, 0.f, 0.f, 0.f};

#pragma unroll
    for (int ks = 0; ks < 8; ++ks) {
        const int kb = ks * 4 + quad;
#pragma unroll
        for (int ni = 0; ni < 8; ++ni) {
            const int wrow = ni * 16 + r;
            bf16x8 b = *(const bf16x8*)&wut_lds[wrow * 256 + ((kb ^ (wrow & 7)) * 8)];
            acc[ni] = __builtin_amdgcn_mfma_f32_16x16x32_bf16(a[ks], b, acc[ni], 0, 0, 0);
        }
    }

    float vals[8][4];
    float gcol[8], bcol[8];
#pragma unroll
    for (int ni = 0; ni < 8; ++ni) {
        const int col = ni * 16 + r;
        const float bias = bupd[col];
        gcol[ni] = gamma[col];
        bcol[ni] = beta[col];
#pragma unroll
        for (int reg = 0; reg < 4; ++reg) vals[ni][reg] = acc[ni][reg] + bias;
    }

#pragma unroll
    for (int reg = 0; reg < 4; ++reg) {
        float s = 0.f, s2 = 0.f;
#pragma unroll
        for (int ni = 0; ni < 8; ++ni) {
            s += vals[ni][reg];
            s2 += vals[ni][reg] * vals[ni][reg];
        }
#pragma unroll
        for (int off = 8; off >= 1; off >>= 1) {
            s += __shfl_xor(s, off, 64);
            s2 += __shfl_xor(s2, off, 64);
        }
        const int row = rowbase + quad * 4 + reg;
        if (row < NNODES) {
            const float mu = s * (1.0f / 128.0f);
            const float var = s2 * (1.0f / 128.0f) - mu * mu;
            const float inv = rsqrtf(var + EPS);
#pragma unroll
            for (int ni = 0; ni < 8; ++ni) {
                const int col = ni * 16 + r;
                float hn = (vals[ni][reg] - mu) * inv * gcol[ni] + bcol[ni];
                float ge = 0.5f * hn * (1.0f + erff(hn * 0.70710678118654752f));
                out[(size_t)row * 128 + col] = xr[ni][reg] + ge;
            }
        }
    }
}

// ---------------------------------------------------------------------------
extern "C" void kernel_launch(void* const* d_in, const int* in_sizes, int n_in,
                              void* d_out, int out_size, void* d_ws, size_t ws_size,
                              hipStream_t stream) {
    const float* x     = (const float*)d_in[0];
    const int*   ei    = (const int*)d_in[1];
    const int*   et    = (const int*)d_in[2];
    const float* Wmsg  = (const float*)d_in[3];
    const float* bmsg  = (const float*)d_in[4];
    const float* Wupd  = (const float*)d_in[5];
    const float* bupd  = (const float*)d_in[6];
    const float* gamma = (const float*)d_in[7];
    const float* beta  = (const float*)d_in[8];
    float* out = (float*)d_out;

    char* ws = (char*)d_ws;
    unsigned short* W6T  = (unsigned short*)(ws + OFF_W6T);
    float*          Bv   = (float*)(ws + OFF_BV);
    unsigned short* WuT  = (unsigned short*)(ws + OFF_WUT);
    unsigned short* Xb   = (unsigned short*)(ws + OFF_XB);
    unsigned short* ABb  = (unsigned short*)(ws + OFF_ABB);
    unsigned short* Agb  = (unsigned short*)(ws + OFF_AGB);
    int*            hist = (int*)(ws + OFF_HIST);
    int*            excl = (int*)(ws + OFF_EXCL);
    int*            curs = (int*)(ws + OFF_CURS);
    int*            bsum = (int*)(ws + OFF_BSUM);
    unsigned*       pack = (unsigned*)(ws + OFF_PACK);

    hipMemsetAsync(hist, 0, NNODES * sizeof(int), stream);

    phase0<<<P0_HIST_END, 256, 0, stream>>>(Wmsg, bmsg, Wupd, x, ei, W6T, Bv, WuT, Xb, hist);
    gemm_ab<<<dim3(MPAD / 64, 3), 256, 0, stream>>>(Xb, W6T, Bv, ABb);
    scan_phase1<<<NSCAN_BLOCKS, 256, 0, stream>>>(hist, excl, bsum);
    scan_phase3<<<NSCAN_BLOCKS, 256, 0, stream>>>(excl, bsum, curs);
    edge_bucket<<<(NEDGES + 255) / 256, 256, 0, stream>>>(ei, et, curs, pack);
    aggregate<<<(NNODES + 3) / 4, 256, 0, stream>>>(pack, excl, hist, ABb, Agb);
    update_mfma<<<MPAD / 64, 256, 0, stream>>>(Xb, Agb, WuT, bupd, gamma, beta, out);
}

// Round 12
// 238.435 us; speedup vs baseline: 3.7585x; 1.0469x over previous
//
#include <hip/hip_runtime.h>
#include <hip/hip_bf16.h>
#include <math.h>

#define HIDDEN 128
#define NNODES 50000
#define NEDGES 600000
#define EPS 1e-5f
#define SCAN_CHUNK 1024
#define NSCAN_BLOCKS ((NNODES + SCAN_CHUNK - 1) / SCAN_CHUNK)  // 49
#define MPAD 50048  // 782 * 64

// phase0 block ranges
#define P0_W6T_END   384
#define P0_BV_END    387
#define P0_WUT_END   515
#define P0_XB_END    (515 + 6256)            // MPAD*128/4/256 = 6256 blocks
#define P0_HIST_END  (P0_XB_END + 2344)      // (NEDGES+255)/256 = 2344 blocks

// Workspace layout (bytes), all 16B-aligned. ABb is FP8 (1B/elem).
#define OFF_W6T  ((size_t)0)            // 768*128*2   = 196,608
#define OFF_BV   ((size_t)196608)       // 768*4       = 3,072   -> 199,680
#define OFF_WUT  ((size_t)199680)       // 128*256*2   = 65,536  -> 265,216
#define OFF_XB   ((size_t)265216)       // 50048*128*2 = 12,812,288 -> 13,077,504
#define OFF_ABB  ((size_t)13077504)     // 50000*768*1 = 38,400,000 -> 51,477,504
#define OFF_AGB  ((size_t)51477504)     // 50048*128*2 = 12,812,288 -> 64,289,792
#define OFF_HIST ((size_t)64289792)     // pad 200,192 -> 64,489,984
#define OFF_EXCL ((size_t)64489984)     // -> 64,690,176
#define OFF_CURS ((size_t)64690176)     // -> 64,890,368
#define OFF_BSUM ((size_t)64890368)     // 256 -> 64,890,624
#define OFF_PACK ((size_t)64890624)     // 600000*4 = 2,400,000

typedef __attribute__((ext_vector_type(8))) short bf16x8;
typedef __attribute__((ext_vector_type(4))) float f32x4;

__device__ inline unsigned short f2bf(float f) {
    union { float f; unsigned u; } c; c.f = f;
    unsigned u = c.u;
    u += 0x7FFF + ((u >> 16) & 1);  // RNE
    return (unsigned short)(u >> 16);
}
__device__ inline float bf2f(unsigned short h) {
    union { unsigned u; float f; } c; c.u = ((unsigned)h) << 16;
    return c.f;
}

// fp8 e4m3fn (OCP) hardware converts; byte-select must be a literal constant
__device__ inline unsigned char f2fp8(float f) {
    int d = __builtin_amdgcn_cvt_pk_fp8_f32(f, f, 0, false);
    return (unsigned char)(d & 0xFF);
}
template <int S>
__device__ inline float fp8f(unsigned q) {
    return __builtin_amdgcn_cvt_f32_fp8(q, S);
}

// ---------------------------------------------------------------------------
// Kernel 0: fused phase-0: weight prep + x->bf16 + dst histogram.
__global__ __launch_bounds__(256) void phase0(const float* __restrict__ Wmsg,
                                              const float* __restrict__ bmsg,
                                              const float* __restrict__ Wupd,
                                              const float* __restrict__ x,
                                              const int* __restrict__ ei,
                                              unsigned short* __restrict__ W6T,
                                              float* __restrict__ Bv,
                                              unsigned short* __restrict__ WuT,
                                              unsigned short* __restrict__ Xb,
                                              int* __restrict__ hist) {
    const int b = blockIdx.x;
    const int tid = threadIdx.x;
    if (b < P0_W6T_END) {
        int idx = b * 256 + tid;
        int col = idx >> 7;
        int k = idx & 127;
        int half = col >= 384;
        int rem = col - half * 384;
        int t = rem >> 7;
        int h = rem & 127;
        W6T[idx] = f2bf(Wmsg[t * 32768 + (half * 128 + k) * 128 + h]);
    } else if (b < P0_BV_END) {
        int idx = (b - P0_W6T_END) * 256 + tid;
        if (idx < 768) Bv[idx] = (idx < 384) ? 0.f : bmsg[idx - 384];
    } else if (b < P0_WUT_END) {
        int idx = (b - P0_BV_END) * 256 + tid;
        int n = idx >> 8;
        int k = idx & 255;
        WuT[idx] = f2bf(Wupd[(size_t)k * 128 + n]);
    } else if (b < P0_XB_END) {
        int i = (b - P0_WUT_END) * 256 + tid;
        int base = i * 4;
        if (base < MPAD * 128) {
            ushort4 o;
            if (base < NNODES * 128) {
                float4 v = *(const float4*)(x + base);
                o.x = f2bf(v.x); o.y = f2bf(v.y); o.z = f2bf(v.z); o.w = f2bf(v.w);
            } else {
                o.x = o.y = o.z = o.w = 0;
            }
            *(ushort4*)(Xb + base) = o;
        }
    } else {
        int e = (b - P0_XB_END) * 256 + tid;
        if (e < NEDGES) atomicAdd(&hist[ei[NEDGES + e]], 1);
    }
}

// ---------------------------------------------------------------------------
// Kernel 2: MFMA GEMM: ABb[50000][768] FP8 = fp8(Xb @ W6T^T + Bv)
__global__ __launch_bounds__(256) void gemm_ab(const unsigned short* __restrict__ Xb,
                                               const unsigned short* __restrict__ W6T,
                                               const float* __restrict__ Bv,
                                               unsigned char* __restrict__ ABb8) {
    __shared__ unsigned char lds_buf[64 * 272];  // 17 KB: xs view (16KB) then fp8 tile
    const int tid = threadIdx.x;
    const int mbase = blockIdx.x * 64;
    const int w = tid >> 6;
    const int nbase = blockIdx.y * 256 + w * 64;
    const int lane = tid & 63;
    const int r = lane & 15;
    const int quad = lane >> 4;

    // Hoisted W6T b-frags (L2-hot, in flight during staging/barriers)
    bf16x8 b[4][4];  // [ks][ni]
#pragma unroll
    for (int ks = 0; ks < 4; ++ks)
#pragma unroll
        for (int ni = 0; ni < 4; ++ni)
            b[ks][ni] = *(const bf16x8*)(W6T + (size_t)(nbase + ni * 16 + r) * 128 + ks * 32 + quad * 8);

    // Stage Xb tile (64 rows x 128 u16) into LDS, swizzled
    unsigned short* xs = (unsigned short*)lds_buf;
#pragma unroll
    for (int i = 0; i < 4; ++i) {
        int item = i * 256 + tid;
        int row = item >> 4;
        int kb = item & 15;
        bf16x8 v = *(const bf16x8*)(Xb + (size_t)(mbase + row) * 128 + kb * 8);
        *(bf16x8*)&xs[row * 128 + ((kb ^ (row & 7)) * 8)] = v;
    }
    __syncthreads();

    f32x4 acc[4][4];
#pragma unroll
    for (int mi = 0; mi < 4; ++mi)
#pragma unroll
        for (int ni = 0; ni < 4; ++ni) acc[mi][ni] = (f32x4){0.f, 0.f, 0.f, 0.f};

#pragma unroll
    for (int ks = 0; ks < 4; ++ks) {
        bf16x8 a[4];
        const int kb = ks * 4 + quad;
#pragma unroll
        for (int mi = 0; mi < 4; ++mi)
            a[mi] = *(const bf16x8*)&xs[(mi * 16 + r) * 128 + ((kb ^ (r & 7)) * 8)];
#pragma unroll
        for (int mi = 0; mi < 4; ++mi)
#pragma unroll
            for (int ni = 0; ni < 4; ++ni)
                acc[mi][ni] = __builtin_amdgcn_mfma_f32_16x16x32_bf16(a[mi], b[ks][ni], acc[mi][ni], 0, 0, 0);
    }

    __syncthreads();  // xs reads done before reusing lds_buf as fp8 tile
    unsigned char (*tile)[272] = (unsigned char(*)[272])lds_buf;

#pragma unroll
    for (int ni = 0; ni < 4; ++ni) {
        const int col_l = w * 64 + ni * 16 + r;
        const float bias = Bv[blockIdx.y * 256 + col_l];
#pragma unroll
        for (int mi = 0; mi < 4; ++mi) {
            f32x4 v = acc[mi][ni];
#pragma unroll
            for (int reg = 0; reg < 4; ++reg) {
                tile[mi * 16 + quad * 4 + reg][col_l] = f2fp8(v[reg] + bias);
            }
        }
    }
    __syncthreads();

    // Coalesced write-out: 64 rows x 256 B per block; 16B/lane-iter.
#pragma unroll
    for (int i = 0; i < 4; ++i) {
        int item = i * 256 + tid;
        int row_l = item >> 4;
        int chunk = item & 15;
        int grow = mbase + row_l;
        if (grow < NNODES) {
            uint4 v = *(const uint4*)&tile[row_l][chunk * 16];
            *(uint4*)(ABb8 + (size_t)grow * 768 + blockIdx.y * 256 + chunk * 16) = v;
        }
    }
}

// ---------------------------------------------------------------------------
// CSR build
__global__ __launch_bounds__(256) void scan_phase1(const int* __restrict__ hist,
                                                   int* __restrict__ excl,
                                                   int* __restrict__ blockSums) {
    __shared__ int lds[256];
    const int blk = blockIdx.x;
    const int t = threadIdx.x;
    const int base = blk * SCAN_CHUNK + t * 4;
    int v[4];
    int s = 0;
#pragma unroll
    for (int i = 0; i < 4; ++i) {
        v[i] = (base + i < NNODES) ? hist[base + i] : 0;
        s += v[i];
    }
    lds[t] = s;
    __syncthreads();
    for (int off = 1; off < 256; off <<= 1) {
        int add = (t >= off) ? lds[t - off] : 0;
        __syncthreads();
        lds[t] += add;
        __syncthreads();
    }
    int incl = lds[t];
    int run = incl - s;
#pragma unroll
    for (int i = 0; i < 4; ++i) {
        if (base + i < NNODES) excl[base + i] = run;
        run += v[i];
    }
    if (t == 255) blockSums[blk] = incl;
}

__global__ __launch_bounds__(256) void scan_phase3(int* __restrict__ excl,
                                                   const int* __restrict__ blockSums,
                                                   int* __restrict__ cursor) {
    __shared__ int s_add;
    const int blk = blockIdx.x;
    const int t = threadIdx.x;
    if (t < 64) {
        int v = (t < blk) ? blockSums[t] : 0;
#pragma unroll
        for (int off = 32; off >= 1; off >>= 1) v += __shfl_xor(v, off, 64);
        if (t == 0) s_add = v;
    }
    __syncthreads();
    const int add = s_add;
    for (int i = t; i < SCAN_CHUNK; i += 256) {
        int idx = blk * SCAN_CHUNK + i;
        if (idx < NNODES) {
            int o = excl[idx] + add;
            excl[idx] = o;
            cursor[idx] = o;
        }
    }
}

// bucket edges by dst; pack dword-offset of fp8 A-row + type:
//   packed = (src*192 + t*32) | (t << 25)
__global__ __launch_bounds__(256) void edge_bucket(const int* __restrict__ ei,
                                                   const int* __restrict__ et,
                                                   int* __restrict__ cursor,
                                                   unsigned* __restrict__ packed) {
    int e = blockIdx.x * 256 + threadIdx.x;
    if (e >= NEDGES) return;
    int src = ei[e];
    int dst = ei[NEDGES + e];
    int t = et[e];
    int pos = atomicAdd(&cursor[dst], 1);
    packed[pos] = (unsigned)(src * 192 + t * 32) | ((unsigned)t << 25);
}

// ---------------------------------------------------------------------------
// Kernel 4: gather aggregation from FP8 table -> normalized bf16 agg.
// One wave per node; paired-edge; 1 dword = 4 fp8 cols per lane per edge.
__global__ __launch_bounds__(256) void aggregate(const unsigned* __restrict__ packed,
                                                 const int* __restrict__ excl,
                                                 const int* __restrict__ hist,
                                                 const unsigned char* __restrict__ ABb8,
                                                 unsigned short* __restrict__ Agb) {
    const int n = blockIdx.x * 4 + (threadIdx.x >> 6);
    const int lane = threadIdx.x & 63;
    if (n >= NNODES) return;
    const int start = excl[n];
    const int deg = hist[n];
    const unsigned* ABu = (const unsigned*)ABb8;

    const int half = lane >> 5;   // which edge of the pair
    const int cl = lane & 31;     // dword index: cols 4*cl .. 4*cl+3

    float s0 = 0.f, s1 = 0.f, s2 = 0.f, s3 = 0.f;
    int c1 = 0, c2 = 0;

    for (int base = 0; base < deg; base += 64) {
        const int m = min(64, deg - base);
        unsigned v = 0;
        if (lane < m) v = packed[start + base + lane];
        int j = 0;
        for (; j + 8 <= m; j += 8) {
            unsigned e0 = __shfl(v, j + 0 + half, 64);
            unsigned e1 = __shfl(v, j + 2 + half, 64);
            unsigned e2 = __shfl(v, j + 4 + half, 64);
            unsigned e3 = __shfl(v, j + 6 + half, 64);
            unsigned q0 = ABu[(e0 & 0x1FFFFFF) + cl];
            unsigned q1 = ABu[(e1 & 0x1FFFFFF) + cl];
            unsigned q2 = ABu[(e2 & 0x1FFFFFF) + cl];
            unsigned q3 = ABu[(e3 & 0x1FFFFFF) + cl];
            int t0 = e0 >> 25, t1 = e1 >> 25, t2 = e2 >> 25, t3 = e3 >> 25;
            c1 += (t0 == 1) + (t1 == 1) + (t2 == 1) + (t3 == 1);
            c2 += (t0 == 2) + (t1 == 2) + (t2 == 2) + (t3 == 2);
            s0 += (fp8f<0>(q0) + fp8f<0>(q1)) + (fp8f<0>(q2) + fp8f<0>(q3));
            s1 += (fp8f<1>(q0) + fp8f<1>(q1)) + (fp8f<1>(q2) + fp8f<1>(q3));
            s2 += (fp8f<2>(q0) + fp8f<2>(q1)) + (fp8f<2>(q2) + fp8f<2>(q3));
            s3 += (fp8f<3>(q0) + fp8f<3>(q1)) + (fp8f<3>(q2) + fp8f<3>(q3));
        }
        for (; j + 2 <= m; j += 2) {
            unsigned e0 = __shfl(v, j + half, 64);
            unsigned q0 = ABu[(e0 & 0x1FFFFFF) + cl];
            int t0 = e0 >> 25;
            c1 += (t0 == 1);
            c2 += (t0 == 2);
            s0 += fp8f<0>(q0); s1 += fp8f<1>(q0);
            s2 += fp8f<2>(q0); s3 += fp8f<3>(q0);
        }
        if (j < m) {  // odd leftover: only half 0 contributes
            unsigned e0 = __shfl(v, j, 64);
            if (half == 0) {
                unsigned q0 = ABu[(e0 & 0x1FFFFFF) + cl];
                int t0 = e0 >> 25;
                c1 += (t0 == 1);
                c2 += (t0 == 2);
                s0 += fp8f<0>(q0); s1 += fp8f<1>(q0);
                s2 += fp8f<2>(q0); s3 += fp8f<3>(q0);
            }
        }
    }

    // combine halves
    s0 += __shfl_xor(s0, 32, 64);
    s1 += __shfl_xor(s1, 32, 64);
    s2 += __shfl_xor(s2, 32, 64);
    s3 += __shfl_xor(s3, 32, 64);
    c1 += __shfl_xor(c1, 32, 64);
    c2 += __shfl_xor(c2, 32, 64);
    const int c0 = deg - c1 - c2;

    // B-half: dword base n*192 + 96, +32 per type
    const unsigned* brow = ABu + (size_t)n * 192 + 96;
    if (c0) {
        unsigned p = brow[cl];
        s0 += c0 * fp8f<0>(p); s1 += c0 * fp8f<1>(p);
        s2 += c0 * fp8f<2>(p); s3 += c0 * fp8f<3>(p);
    }
    if (c1) {
        unsigned p = brow[32 + cl];
        s0 += c1 * fp8f<0>(p); s1 += c1 * fp8f<1>(p);
        s2 += c1 * fp8f<2>(p); s3 += c1 * fp8f<3>(p);
    }
    if (c2) {
        unsigned p = brow[64 + cl];
        s0 += c2 * fp8f<0>(p); s1 += c2 * fp8f<1>(p);
        s2 += c2 * fp8f<2>(p); s3 += c2 * fp8f<3>(p);
    }

    const float inv = 1.0f / fmaxf((float)deg, 1.0f);
    if (half == 0) {
        uint2 o;
        o.x = (unsigned)f2bf(s0 * inv) | ((unsigned)f2bf(s1 * inv) << 16);
        o.y = (unsigned)f2bf(s2 * inv) | ((unsigned)f2bf(s3 * inv) << 16);
        ((uint2*)(Agb + (size_t)n * 128))[cl] = o;
    }
}

// ---------------------------------------------------------------------------
// Kernel 5: MFMA update with LDS-staged WuT; residual via identity-MFMA.
__global__ __launch_bounds__(256) void update_mfma(const unsigned short* __restrict__ Xb,
                                                   const unsigned short* __restrict__ Agb,
                                                   const unsigned short* __restrict__ WuT,
                                                   const float* __restrict__ bupd,
                                                   const float* __restrict__ gamma,
                                                   const float* __restrict__ beta,
                                                   float* __restrict__ out) {
    __shared__ unsigned short wut_lds[128 * 256];  // 64 KB, swizzled

    const int tid = threadIdx.x;
    const int rowbase = blockIdx.x * 64 + (tid >> 6) * 16;
    const int lane = tid & 63;
    const int r = lane & 15;
    const int quad = lane >> 4;

    bf16x8 a[8];
#pragma unroll
    for (int ks = 0; ks < 4; ++ks)
        a[ks] = *(const bf16x8*)(Xb + (size_t)(rowbase + r) * 128 + ks * 32 + quad * 8);
#pragma unroll
    for (int ks = 4; ks < 8; ++ks)
        a[ks] = *(const bf16x8*)(Agb + (size_t)(rowbase + r) * 128 + (ks - 4) * 32 + quad * 8);

#pragma unroll
    for (int it = 0; it < 16; ++it) {
        int frag = it * 256 + tid;
        int wrow = frag >> 5;
        int kb = frag & 31;
        bf16x8 v = *(const bf16x8*)(WuT + (size_t)wrow * 256 + kb * 8);
        *(bf16x8*)&wut_lds[wrow * 256 + ((kb ^ (wrow & 7)) * 8)] = v;
    }

    // identity extraction of residual x (A-layout -> C-layout)
    bf16x8 e0, e1;
    const int tgt0 = r;
    const int tgt1 = 16 + r;
#pragma unroll
    for (int t = 0; t < 8; ++t) {
        e0[t] = (short)((quad * 8 + t == tgt0) ? 0x3F80 : 0);
        e1[t] = (short)((quad * 8 + t == tgt1) ? 0x3F80 : 0);
    }
    f32x4 xr[8];
#pragma unroll
    for (int ni = 0; ni < 8; ++ni) {
        f32x4 z = (f32x4){0.f, 0.f, 0.f, 0.f};
        xr[ni] = __builtin_amdgcn_mfma_f32_16x16x32_bf16(a[ni >> 1], (ni & 1) ? e1 : e0, z, 0, 0, 0);
    }

    __syncthreads();

    f32x4 acc[8];
#pragma unroll
    for (int ni = 0; ni < 8; ++ni) acc[ni] = (f32x4){0.f, 0.f, 0.f, 0.f};

#pragma unroll
    for (int ks = 0; ks < 8; ++ks) {
        const int kb = ks * 4 + quad;
#pragma unroll
        for (int ni = 0; ni < 8; ++ni) {
            const int wrow = ni * 16 + r;
            bf16x8 b = *(const bf16x8*)&wut_lds[wrow * 256 + ((kb ^ (wrow & 7)) * 8)];
            acc[ni] = __builtin_amdgcn_mfma_f32_16x16x32_bf16(a[ks], b, acc[ni], 0, 0, 0);
        }
    }

    float vals[8][4];
    float gcol[8], bcol[8];
#pragma unroll
    for (int ni = 0; ni < 8; ++ni) {
        const int col = ni * 16 + r;
        const float bias = bupd[col];
        gcol[ni] = gamma[col];
        bcol[ni] = beta[col];
#pragma unroll
        for (int reg = 0; reg < 4; ++reg) vals[ni][reg] = acc[ni][reg] + bias;
    }

#pragma unroll
    for (int reg = 0; reg < 4; ++reg) {
        float s = 0.f, s2 = 0.f;
#pragma unroll
        for (int ni = 0; ni < 8; ++ni) {
            s += vals[ni][reg];
            s2 += vals[ni][reg] * vals[ni][reg];
        }
#pragma unroll
        for (int off = 8; off >= 1; off >>= 1) {
            s += __shfl_xor(s, off, 64);
            s2 += __shfl_xor(s2, off, 64);
        }
        const int row = rowbase + quad * 4 + reg;
        if (row < NNODES) {
            const float mu = s * (1.0f / 128.0f);
            const float var = s2 * (1.0f / 128.0f) - mu * mu;
            const float inv = rsqrtf(var + EPS);
#pragma unroll
            for (int ni = 0; ni < 8; ++ni) {
                const int col = ni * 16 + r;
                float hn = (vals[ni][reg] - mu) * inv * gcol[ni] + bcol[ni];
                float ge = 0.5f * hn * (1.0f + erff(hn * 0.70710678118654752f));
                out[(size_t)row * 128 + col] = xr[ni][reg] + ge;
            }
        }
    }
}

// ---------------------------------------------------------------------------
extern "C" void kernel_launch(void* const* d_in, const int* in_sizes, int n_in,
                              void* d_out, int out_size, void* d_ws, size_t ws_size,
                              hipStream_t stream) {
    const float* x     = (const float*)d_in[0];
    const int*   ei    = (const int*)d_in[1];
    const int*   et    = (const int*)d_in[2];
    const float* Wmsg  = (const float*)d_in[3];
    const float* bmsg  = (const float*)d_in[4];
    const float* Wupd  = (const float*)d_in[5];
    const float* bupd  = (const float*)d_in[6];
    const float* gamma = (const float*)d_in[7];
    const float* beta  = (const float*)d_in[8];
    float* out = (float*)d_out;

    char* ws = (char*)d_ws;
    unsigned short* W6T  = (unsigned short*)(ws + OFF_W6T);
    float*          Bv   = (float*)(ws + OFF_BV);
    unsigned short* WuT  = (unsigned short*)(ws + OFF_WUT);
    unsigned short* Xb   = (unsigned short*)(ws + OFF_XB);
    unsigned char*  ABb8 = (unsigned char*)(ws + OFF_ABB);
    unsigned short* Agb  = (unsigned short*)(ws + OFF_AGB);
    int*            hist = (int*)(ws + OFF_HIST);
    int*            excl = (int*)(ws + OFF_EXCL);
    int*            curs = (int*)(ws + OFF_CURS);
    int*            bsum = (int*)(ws + OFF_BSUM);
    unsigned*       pack = (unsigned*)(ws + OFF_PACK);

    (void)hipMemsetAsync(hist, 0, NNODES * sizeof(int), stream);

    phase0<<<P0_HIST_END, 256, 0, stream>>>(Wmsg, bmsg, Wupd, x, ei, W6T, Bv, WuT, Xb, hist);
    gemm_ab<<<dim3(MPAD / 64, 3), 256, 0, stream>>>(Xb, W6T, Bv, ABb8);
    scan_phase1<<<NSCAN_BLOCKS, 256, 0, stream>>>(hist, excl, bsum);
    scan_phase3<<<NSCAN_BLOCKS, 256, 0, stream>>>(excl, bsum, curs);
    edge_bucket<<<(NEDGES + 255) / 256, 256, 0, stream>>>(ei, et, curs, pack);
    aggregate<<<(NNODES + 3) / 4, 256, 0, stream>>>(pack, excl, hist, ABb8, Agb);
    update_mfma<<<MPAD / 64, 256, 0, stream>>>(Xb, Agb, WuT, bupd, gamma, beta, out);
}